// Round 8
// baseline (360.982 us; speedup 1.0000x reference)
//
#include <hip/hip_runtime.h>
#include <hip/hip_bf16.h>

#define NPIX 16384
#define NVOC 8192
#define CHUNK 128

typedef short short8v __attribute__((ext_vector_type(8)));
typedef float floatx4 __attribute__((ext_vector_type(4)));

// ---- ws layout (bytes) ----
// region A (0..8 MB): zebf during cvt/gemm -> blist after gemm -> part tail
#define WS_ZEBF   0u          // 16384*256 bf16 = 8388608 (dead after k_gemm)
#define WS_BLIST  0u          // 128*16384 i32 = 8388608 (alias, post-gemm)
#define WS_PART   0u          // 256 f32 (alias, post-rescore; blist dead)
// region B: cbbf during gemm -> pk/tau after gemm
#define WS_CBBF   8388608u    // 8192*256 bf16 = 4194304 (dead after k_gemm)
#define WS_PK     8388608u    // 16384 u64 = 131072 (alias, post-gemm)
#define WS_TAU    8519680u    // 16384 f32 = 65536 (alias, post-gemm)
// persistent
#define WS_ZEF    12582912u   // 16384*256 f32 = 16777216
#define WS_MIN    29360128u   // 128*16384 f32 = 8388608
#define WS_BN     37748736u   // 8192 f32
#define WS_AN     37781504u   // 16384 f32
#define WS_BCNT   37847040u   // 128 i32 (pad to 512)
#define WS_BMAXU  37847552u   // 1 u32 (pad)

__device__ __forceinline__ short f2bf(float v) {
  __bf16 h = (__bf16)v;
  return __builtin_bit_cast(short, h);
}

__device__ __forceinline__ float rl(float v, int l) {
  return __uint_as_float(__builtin_amdgcn_readlane(__float_as_uint(v), l));
}

__device__ __forceinline__ unsigned long long packdj(float d, int j) {
  return ((unsigned long long)__float_as_uint(d) << 32) | (unsigned int)j;
}

__device__ __forceinline__ void gll16(const void* g, void* l) {
  __builtin_amdgcn_global_load_lds(
      (const __attribute__((address_space(1))) void*)g,
      (__attribute__((address_space(3))) void*)l, 16, 0, 0);
}

// numpy pairwise-sum of 128 squares
__device__ __forceinline__ float np_pairwise128_sq(const float* x, int stride) {
  float r[8];
#pragma unroll
  for (int j = 0; j < 8; ++j) {
    float v = x[j * stride];
    r[j] = __fmul_rn(v, v);
  }
#pragma unroll
  for (int i = 1; i < 16; ++i) {
#pragma unroll
    for (int j = 0; j < 8; ++j) {
      float v = x[(i * 8 + j) * stride];
      r[j] = __fadd_rn(r[j], __fmul_rn(v, v));
    }
  }
  return __fadd_rn(__fadd_rn(__fadd_rn(r[0], r[1]), __fadd_rn(r[2], r[3])),
                   __fadd_rn(__fadd_rn(r[4], r[5]), __fadd_rn(r[6], r[7])));
}

// ||codebook_j||^2 (numpy order) + global max(bn) via atomicMax on bits
__global__ __launch_bounds__(256) void k_bnorm(const float* __restrict__ cb,
                                               float* __restrict__ bn,
                                               unsigned* __restrict__ bmaxu) {
  __shared__ float rows[64][257];
  int tid = threadIdx.x;
  int c0 = blockIdx.x * 64;
  for (int r = 0; r < 64; ++r)
    rows[r][tid] = cb[(size_t)(c0 + r) * 256 + tid];
  __syncthreads();
  if (tid < 64) {
    float a = np_pairwise128_sq(&rows[tid][0], 1);
    float b = np_pairwise128_sq(&rows[tid][128], 1);
    float v = __fadd_rn(a, b);
    bn[c0 + tid] = v;
    atomicMax(bmaxu, __float_as_uint(v));  // v >= 0: bit order == float order
  }
}

// ze [16][256][1024] fp32 -> zebf (bf16) + zef (fp32) [16384][256]; fused anorm
__global__ __launch_bounds__(256) void k_cvt_ze(const float* __restrict__ ze,
                                                short* __restrict__ zebf,
                                                float* __restrict__ zef,
                                                float* __restrict__ an) {
  __shared__ float t[64][132];
  int tid = threadIdx.x;
  int p0 = blockIdx.x * 64;
  int b = p0 >> 10, hw0 = p0 & 1023;
  const float* src = ze + (size_t)b * 262144 + hw0;
  float apart = 0.f;
  for (int half = 0; half < 2; ++half) {
    if (half) __syncthreads();
    {
      int hw = tid & 63, cq = tid >> 6;
#pragma unroll
      for (int i = 0; i < 32; ++i) {
        int cl = i * 4 + cq;
        t[hw][cl] = src[(size_t)(half * 128 + cl) * 1024 + hw];
      }
    }
    __syncthreads();
    int r = tid >> 2, cg = tid & 3;
    float* fd = zef + (size_t)(p0 + r) * 256 + half * 128 + cg * 32;
    short* bd = zebf + (size_t)(p0 + r) * 256 + half * 128 + cg * 32;
#pragma unroll
    for (int s = 0; s < 8; ++s) {
      float4 v = *reinterpret_cast<const float4*>(&t[r][cg * 32 + s * 4]);
      *reinterpret_cast<float4*>(fd + s * 4) = v;
    }
#pragma unroll
    for (int s = 0; s < 4; ++s) {
      short8v v8;
#pragma unroll
      for (int e = 0; e < 8; ++e) v8[e] = f2bf(t[r][cg * 32 + s * 8 + e]);
      *reinterpret_cast<short8v*>(bd + s * 8) = v8;
    }
    if (tid < 64) {
      float a = np_pairwise128_sq(&t[tid][0], 1);
      apart = half ? __fadd_rn(apart, a) : a;
    }
  }
  if (tid < 64) an[p0 + tid] = apart;
}

// cb -> bf16; also init bmax
__global__ __launch_bounds__(256) void k_cvt_cb(const float* __restrict__ cb,
                                                short* __restrict__ cbbf,
                                                unsigned* __restrict__ bmaxu) {
  int tid = threadIdx.x;
  if (blockIdx.x == 0 && tid == 0) bmaxu[0] = 0u;
  size_t i = ((size_t)blockIdx.x * 256 + tid) * 8;
  float4 a = *reinterpret_cast<const float4*>(cb + i);
  float4 b = *reinterpret_cast<const float4*>(cb + i + 4);
  short8v v;
  v[0] = f2bf(a.x); v[1] = f2bf(a.y); v[2] = f2bf(a.z); v[3] = f2bf(a.w);
  v[4] = f2bf(b.x); v[5] = f2bf(b.y); v[6] = f2bf(b.z); v[7] = f2bf(b.w);
  *reinterpret_cast<short8v*>(cbbf + i) = v;
}

// N-streaming bf16 MFMA distance GEMM.
// 256 blocks (1/CU, co-resident), 512 threads (8 waves = 2M x 4N).
// Block owns 64 pixels; A (64x256) staged once, fragments pinned in registers.
// B streamed as 128 tiles of 64 cols x 256 K (32 KB) via triple buffer with
// counted vmcnt(4) (tiles t+1,t+2 always in flight; tail peeled).
// Per iter: colmin over the tile's 64 cols -> wsmin[t][p].
__global__ __launch_bounds__(512, 2) void k_gemm(const short* __restrict__ zebf,
                                                 const short* __restrict__ cbbf,
                                                 const float* __restrict__ bn,
                                                 float* __restrict__ wsmin) {
  __shared__ short lds[65536];  // [0,16384): A ; B bufs at 16384/32768/49152
  __shared__ __align__(16) float sm[64][4];
  int tid = threadIdx.x;
  int lane = tid & 63, w = tid >> 6;
  int wr = w >> 2, wc = w & 3;
  int g = lane >> 4, r16 = lane & 15;
  int p0 = blockIdx.x * 64;
  const short* Aq = zebf + (size_t)p0 * 256;

  // ---- prologue: stage A + B0 + B1 (pre-swizzled source, linear LDS dest)
#pragma unroll
  for (int s = 0; s < 4; ++s) {
    int cid = tid + s * 512;
    int row = cid >> 5, x = cid & 31;
    gll16(Aq + row * 256 + (x ^ (row & 7)) * 8, &lds[cid * 8]);
  }
#pragma unroll
  for (int bt = 0; bt < 2; ++bt) {
    const short* src = cbbf + (size_t)bt * 16384;
#pragma unroll
    for (int s = 0; s < 4; ++s) {
      int cid = tid + s * 512;
      int col = cid >> 5, x = cid & 31;
      gll16(src + col * 256 + (x ^ (col & 7)) * 8,
            &lds[16384 + bt * 16384 + cid * 8]);
    }
  }
  asm volatile("s_waitcnt vmcnt(8)" ::: "memory");  // A landed
  __builtin_amdgcn_s_barrier();

  // A fragments: pinned in registers for the whole kernel (2 rf x 8 ks)
  short8v af0[8], af1[8];
  {
    int row0 = wr * 32 + r16;
    int row1 = wr * 32 + 16 + r16;
#pragma unroll
    for (int ks = 0; ks < 8; ++ks) {
      af0[ks] = *reinterpret_cast<const short8v*>(
          &lds[row0 * 256 + (((ks * 4 + g) ^ (row0 & 7)) * 8)]);
      af1[ks] = *reinterpret_cast<const short8v*>(
          &lds[row1 * 256 + (((ks * 4 + g) ^ (row1 & 7)) * 8)]);
    }
  }
  asm volatile("s_waitcnt vmcnt(4)" ::: "memory");  // B0 landed (B1 in flight)
  __builtin_amdgcn_s_barrier();

  int colL = wc * 16 + r16;  // this lane's B column within the tile
  int cxor = colL & 7;
  int cA = 16384, cB = 32768, cC = 49152;

  for (int t = 0; t < 128; ++t) {
    float Bj = bn[t * 64 + colL];  // issued first; covered by counted vmcnt
    if (t + 2 < 128) {             // stage B(t+2) into cC
      const short* src = cbbf + (size_t)(t + 2) * 16384;
#pragma unroll
      for (int s = 0; s < 4; ++s) {
        int cid = tid + s * 512;
        int col = cid >> 5, x = cid & 31;
        gll16(src + col * 256 + (x ^ (col & 7)) * 8, &lds[cC + cid * 8]);
      }
    }
    short8v bf[8];
#pragma unroll
    for (int ks = 0; ks < 8; ++ks)
      bf[ks] = *reinterpret_cast<const short8v*>(
          &lds[cA + colL * 256 + (((ks * 4 + g) ^ cxor) * 8)]);
    asm volatile("s_waitcnt lgkmcnt(0)" ::: "memory");
    __builtin_amdgcn_sched_barrier(0);
    __builtin_amdgcn_s_setprio(1);
    floatx4 a0 = {0.f, 0.f, 0.f, 0.f}, a1 = {0.f, 0.f, 0.f, 0.f};
#pragma unroll
    for (int ks = 0; ks < 8; ++ks) {  // k-ascending: bit-identical t_hat
      a0 = __builtin_amdgcn_mfma_f32_16x16x32_bf16(af0[ks], bf[ks], a0, 0, 0, 0);
      a1 = __builtin_amdgcn_mfma_f32_16x16x32_bf16(af1[ks], bf[ks], a1, 0, 0, 0);
    }
    __builtin_amdgcn_s_setprio(0);
    // counted wait: drains B(t+1)+Bj, leaves B(t+2) in flight (tail: drain all)
    if (t < 126)
      asm volatile("s_waitcnt vmcnt(4)" ::: "memory");
    else
      asm volatile("s_waitcnt vmcnt(0)" ::: "memory");
    // colmin over this tile's 64 cols: 16 r16-lanes via shfl, 4 wc via LDS
    float t0[4], t1[4];
#pragma unroll
    for (int rr = 0; rr < 4; ++rr) {
      t0[rr] = __builtin_fmaf(-2.0f, a0[rr], Bj);
      t1[rr] = __builtin_fmaf(-2.0f, a1[rr], Bj);
    }
#pragma unroll
    for (int off = 1; off < 16; off <<= 1) {
#pragma unroll
      for (int rr = 0; rr < 4; ++rr) {
        t0[rr] = fminf(t0[rr], __shfl_xor(t0[rr], off, 16));
        t1[rr] = fminf(t1[rr], __shfl_xor(t1[rr], off, 16));
      }
    }
    if (r16 == 0) {
#pragma unroll
      for (int rr = 0; rr < 4; ++rr) {
        sm[wr * 32 + g * 4 + rr][wc] = t0[rr];
        sm[wr * 32 + 16 + g * 4 + rr][wc] = t1[rr];
      }
    }
    asm volatile("s_waitcnt lgkmcnt(0)" ::: "memory");  // sm writes visible
    __builtin_amdgcn_s_barrier();
    if (tid < 64) {
      float4 v = *reinterpret_cast<const float4*>(&sm[tid][0]);
      wsmin[(size_t)t * NPIX + p0 + tid] =
          fminf(fminf(v.x, v.y), fminf(v.z, v.w));
    }
    __builtin_amdgcn_s_barrier();  // protect sm for next iter
    int tmp = cA; cA = cB; cB = cC; cC = tmp;
  }
}

// per-pixel global min over 128 colblocks -> tau; init pk. No atomics.
__global__ __launch_bounds__(256) void k_tau(const float* __restrict__ wsmin,
                                             const float* __restrict__ an,
                                             const unsigned* __restrict__ bmaxu,
                                             float* __restrict__ tau,
                                             unsigned long long* __restrict__ pk) {
  __shared__ float sm[4][64];
  int tid = threadIdx.x;
  int px = tid & 63, q = tid >> 6;
  int p = blockIdx.x * 64 + px;
  float m0 = 3.4e38f, m1 = 3.4e38f, m2 = 3.4e38f, m3 = 3.4e38f;
#pragma unroll
  for (int i = 0; i < 8; ++i) {
    int c = q * 32 + i * 4;
    m0 = fminf(m0, wsmin[(size_t)c * NPIX + p]);
    m1 = fminf(m1, wsmin[(size_t)(c + 1) * NPIX + p]);
    m2 = fminf(m2, wsmin[(size_t)(c + 2) * NPIX + p]);
    m3 = fminf(m3, wsmin[(size_t)(c + 3) * NPIX + p]);
  }
  sm[q][px] = fminf(fminf(m0, m1), fminf(m2, m3));
  __syncthreads();
  if (tid < 64) {
    float m = fminf(fminf(sm[0][tid], sm[1][tid]), fminf(sm[2][tid], sm[3][tid]));
    float bmaxf = sqrtf(__uint_as_float(bmaxu[0]));
    tau[p] = m + 0.017f * sqrtf(an[p]) * bmaxf + 2e-4f;
    pk[p] = ~0ull;
  }
}

// per-colblock compaction of flagged pixels, ascending p, zero atomics.
__global__ __launch_bounds__(256) void k_compact(const float* __restrict__ wsmin,
                                                 const float* __restrict__ tau,
                                                 int* __restrict__ bcnt,
                                                 int* __restrict__ blist) {
  __shared__ int wbase[4];
  __shared__ int running;
  int c = blockIdx.x;
  const float* row = wsmin + (size_t)c * NPIX;
  int* dst = blist + (size_t)c * NPIX;
  int tid = threadIdx.x;
  int lane = tid & 63, wv = tid >> 6;
  if (tid == 0) running = 0;
  __syncthreads();
  for (int base = 0; base < NPIX; base += 256) {
    int p = base + tid;
    bool flag = row[p] <= tau[p];
    unsigned long long mask = __ballot(flag);
    int cnt = __popcll(mask);
    int pre = __popcll(mask & ((1ull << lane) - 1ull));
    if (lane == 0) wbase[wv] = cnt;
    __syncthreads();
    if (tid == 0) {
      int r = running;
#pragma unroll
      for (int w2 = 0; w2 < 4; ++w2) {
        int t = wbase[w2];
        wbase[w2] = r;
        r += t;
      }
      running = r;
    }
    __syncthreads();
    if (flag) dst[wbase[wv] + pre] = p;
    __syncthreads();
  }
  if (tid == 0) bcnt[c] = running;
}

// bucketed exact fp32 rescore, persistent grid.
__global__ __launch_bounds__(256) void k_rescore_b(
    const float* __restrict__ zef, const float* __restrict__ cb,
    const float* __restrict__ an, const float* __restrict__ bn,
    const int* __restrict__ bcnt, const int* __restrict__ blist,
    unsigned long long* __restrict__ pk) {
  __shared__ float cst[256][64];
  int tid = threadIdx.x;
  int lane = tid & 63, wv = tid >> 6;
  for (int id = blockIdx.x; id < 128 * 128; id += 512) {
    int c = id & 127;
    int chunk = id >> 7;
    int n = bcnt[c];
    int base = chunk * CHUNK;
    if (base >= n) continue;
    int cnt_here = min(CHUNK, n - base);
    __syncthreads();
    {
      int j = tid >> 2, kq = tid & 3;
      const float* src = cb + (size_t)(c * 64 + j) * 256 + kq * 64;
#pragma unroll
      for (int i = 0; i < 16; ++i) {
        float4 v = *reinterpret_cast<const float4*>(src + i * 4);
        int k = kq * 64 + i * 4;
        cst[k][j] = v.x; cst[k + 1][j] = v.y;
        cst[k + 2][j] = v.z; cst[k + 3][j] = v.w;
      }
    }
    __syncthreads();
    int j_global = c * 64 + lane;
    float bnj = bn[j_global];
    for (int g0 = wv * 4; g0 < cnt_here; g0 += 16) {
      int p[4];
      float4 z[4];
      float ap[4];
#pragma unroll
      for (int gi = 0; gi < 4; ++gi) {
        int idx = base + min(g0 + gi, cnt_here - 1);
        p[gi] = blist[(size_t)c * NPIX + idx];
        z[gi] = *reinterpret_cast<const float4*>(zef + (size_t)p[gi] * 256 +
                                                 lane * 4);
        ap[gi] = an[p[gi]];
      }
      float acc0 = 0.f, acc1 = 0.f, acc2 = 0.f, acc3 = 0.f;
#pragma unroll 8
      for (int k4 = 0; k4 < 64; ++k4) {
#pragma unroll
        for (int kk = 0; kk < 4; ++kk) {
          float cv = cst[k4 * 4 + kk][lane];
          float z0 = (kk == 0) ? z[0].x : (kk == 1) ? z[0].y : (kk == 2) ? z[0].z : z[0].w;
          float z1 = (kk == 0) ? z[1].x : (kk == 1) ? z[1].y : (kk == 2) ? z[1].z : z[1].w;
          float z2 = (kk == 0) ? z[2].x : (kk == 1) ? z[2].y : (kk == 2) ? z[2].z : z[2].w;
          float z3 = (kk == 0) ? z[3].x : (kk == 1) ? z[3].y : (kk == 2) ? z[3].z : z[3].w;
          acc0 = __builtin_fmaf(rl(z0, k4), cv, acc0);
          acc1 = __builtin_fmaf(rl(z1, k4), cv, acc1);
          acc2 = __builtin_fmaf(rl(z2, k4), cv, acc2);
          acc3 = __builtin_fmaf(rl(z3, k4), cv, acc3);
        }
      }
      float dv[4] = {acc0, acc1, acc2, acc3};
#pragma unroll
      for (int gi = 0; gi < 4; ++gi) {
        float d = __fsub_rn(__fadd_rn(ap[gi], bnj), 2.0f * dv[gi]);
        unsigned long long q = packdj(d, j_global);
#pragma unroll
        for (int off = 1; off < 64; off <<= 1) {
          unsigned long long q2 = __shfl_xor(q, off);
          q = q2 < q ? q2 : q;
        }
        if (lane == 0) atomicMin(&pk[p[gi]], q);
      }
    }
  }
}

__global__ __launch_bounds__(256) void k_gather(const float* __restrict__ ze,
                                                const float* __restrict__ cb,
                                                const unsigned long long* __restrict__ pk,
                                                float* __restrict__ out_zq,
                                                float* __restrict__ out_idx,
                                                float* __restrict__ part) {
  __shared__ float qrow[64][257];
  __shared__ int sidx[64];
  int tid = threadIdx.x;
  int p0 = blockIdx.x * 64;
  int b = p0 >> 10, hw0 = p0 & 1023;
  if (tid < 64) {
    int bi = (int)(unsigned int)(pk[p0 + tid] & 0xffffffffull);
    sidx[tid] = bi;
    out_idx[p0 + tid] = (float)bi;
  }
  __syncthreads();
  for (int r = 0; r < 64; ++r)
    qrow[r][tid] = cb[(size_t)sidx[r] * 256 + tid];
  __syncthreads();
  float lsum = 0.f;
  size_t zbase = (size_t)b * 262144 + hw0;
#pragma unroll 4
  for (int i = 0; i < 64; ++i) {
    int px = tid & 63;
    int c = i * 4 + (tid >> 6);
    float qv = qrow[px][c];
    size_t gi = zbase + (size_t)c * 1024 + px;
    float zev = ze[gi];
    out_zq[gi] = __fadd_rn(zev, __fsub_rn(qv, zev));
    float d = zev - qv;
    lsum = __builtin_fmaf(d, d, lsum);
  }
#pragma unroll
  for (int off = 32; off; off >>= 1) lsum += __shfl_xor(lsum, off, 64);
  __shared__ float wsum[4];
  if ((tid & 63) == 0) wsum[tid >> 6] = lsum;
  __syncthreads();
  if (tid == 0) part[blockIdx.x] = (wsum[0] + wsum[1]) + (wsum[2] + wsum[3]);
}

__global__ __launch_bounds__(256) void k_final(const float* __restrict__ part,
                                               float* __restrict__ out0) {
  int tid = threadIdx.x;
  float s = part[tid];
#pragma unroll
  for (int off = 32; off; off >>= 1) s += __shfl_xor(s, off, 64);
  __shared__ float wsum[4];
  if ((tid & 63) == 0) wsum[tid >> 6] = s;
  __syncthreads();
  if (tid == 0)
    out0[0] = 1.25f * ((wsum[0] + wsum[1]) + (wsum[2] + wsum[3])) / 4194304.0f;
}

extern "C" void kernel_launch(void* const* d_in, const int* in_sizes, int n_in,
                              void* d_out, int out_size, void* d_ws, size_t ws_size,
                              hipStream_t stream) {
  const float* ze = (const float*)d_in[0];
  const float* cb = (const float*)d_in[1];
  float* out = (float*)d_out;
  char* ws = (char*)d_ws;
  short* zebf = (short*)(ws + WS_ZEBF);
  short* cbbf = (short*)(ws + WS_CBBF);
  float* zef = (float*)(ws + WS_ZEF);
  float* bn = (float*)(ws + WS_BN);
  float* an = (float*)(ws + WS_AN);
  float* wsmin = (float*)(ws + WS_MIN);
  float* tau = (float*)(ws + WS_TAU);
  int* blist = (int*)(ws + WS_BLIST);
  int* bcnt = (int*)(ws + WS_BCNT);
  unsigned* bmaxu = (unsigned*)(ws + WS_BMAXU);
  unsigned long long* pk = (unsigned long long*)(ws + WS_PK);
  float* part = (float*)(ws + WS_PART);
  float* out_loss = out;
  float* out_zq = out + 1;
  float* out_idx = out + 1 + 4194304;

  k_cvt_ze<<<256, 256, 0, stream>>>(ze, zebf, zef, an);
  k_cvt_cb<<<1024, 256, 0, stream>>>(cb, cbbf, bmaxu);
  k_bnorm<<<128, 256, 0, stream>>>(cb, bn, bmaxu);
  k_gemm<<<256, 512, 0, stream>>>(zebf, cbbf, bn, wsmin);
  k_tau<<<256, 256, 0, stream>>>(wsmin, an, bmaxu, tau, pk);
  k_compact<<<128, 256, 0, stream>>>(wsmin, tau, bcnt, blist);
  k_rescore_b<<<512, 256, 0, stream>>>(zef, cb, an, bn, bcnt, blist, pk);
  k_gather<<<256, 256, 0, stream>>>(ze, cb, pk, out_zq, out_idx, part);
  k_final<<<1, 256, 0, stream>>>(part, out_loss);
}

// Round 9
// 224.058 us; speedup vs baseline: 1.6111x; 1.6111x over previous
//
#include <hip/hip_runtime.h>
#include <hip/hip_bf16.h>

#define NPIX 16384
#define NVOC 8192
#define CHUNK 128

typedef short short8v __attribute__((ext_vector_type(8)));
typedef float floatx4 __attribute__((ext_vector_type(4)));

// ---- ws layout (bytes) ----
// region A (0..8 MB): zebf during cvt/gemm -> blist after gemm -> part tail
#define WS_ZEBF   0u          // 16384*256 bf16 = 8388608 (dead after k_gemm)
#define WS_BLIST  0u          // 128*16384 i32 = 8388608 (alias, post-gemm)
#define WS_PART   0u          // 256 f32 (alias, post-rescore; blist dead)
// region B: cbbf during gemm -> pk/tau after gemm
#define WS_CBBF   8388608u    // 8192*256 bf16 = 4194304 (dead after k_gemm)
#define WS_PK     8388608u    // 16384 u64 = 131072 (alias, post-gemm)
#define WS_TAU    8519680u    // 16384 f32 = 65536 (alias, post-gemm)
// persistent
#define WS_ZEF    12582912u   // 16384*256 f32 = 16777216
#define WS_MIN    29360128u   // 128*16384 f32 = 8388608
#define WS_BN     37748736u   // 8192 f32
#define WS_AN     37781504u   // 16384 f32
#define WS_BCNT   37847040u   // 128 i32 (pad to 512)
#define WS_BMAXU  37847552u   // 1 u32 (pad)

__device__ __forceinline__ short f2bf(float v) {
  __bf16 h = (__bf16)v;
  return __builtin_bit_cast(short, h);
}

__device__ __forceinline__ float rl(float v, int l) {
  return __uint_as_float(__builtin_amdgcn_readlane(__float_as_uint(v), l));
}

__device__ __forceinline__ unsigned long long packdj(float d, int j) {
  return ((unsigned long long)__float_as_uint(d) << 32) | (unsigned int)j;
}

__device__ __forceinline__ void gll16(const void* g, void* l) {
  __builtin_amdgcn_global_load_lds(
      (const __attribute__((address_space(1))) void*)g,
      (__attribute__((address_space(3))) void*)l, 16, 0, 0);
}

// numpy pairwise-sum of 128 squares
__device__ __forceinline__ float np_pairwise128_sq(const float* x, int stride) {
  float r[8];
#pragma unroll
  for (int j = 0; j < 8; ++j) {
    float v = x[j * stride];
    r[j] = __fmul_rn(v, v);
  }
#pragma unroll
  for (int i = 1; i < 16; ++i) {
#pragma unroll
    for (int j = 0; j < 8; ++j) {
      float v = x[(i * 8 + j) * stride];
      r[j] = __fadd_rn(r[j], __fmul_rn(v, v));
    }
  }
  return __fadd_rn(__fadd_rn(__fadd_rn(r[0], r[1]), __fadd_rn(r[2], r[3])),
                   __fadd_rn(__fadd_rn(r[4], r[5]), __fadd_rn(r[6], r[7])));
}

// ||codebook_j||^2 (numpy order) + global max(bn) via atomicMax on bits
__global__ __launch_bounds__(256) void k_bnorm(const float* __restrict__ cb,
                                               float* __restrict__ bn,
                                               unsigned* __restrict__ bmaxu) {
  __shared__ float rows[64][257];
  int tid = threadIdx.x;
  int c0 = blockIdx.x * 64;
  for (int r = 0; r < 64; ++r)
    rows[r][tid] = cb[(size_t)(c0 + r) * 256 + tid];
  __syncthreads();
  if (tid < 64) {
    float a = np_pairwise128_sq(&rows[tid][0], 1);
    float b = np_pairwise128_sq(&rows[tid][128], 1);
    float v = __fadd_rn(a, b);
    bn[c0 + tid] = v;
    atomicMax(bmaxu, __float_as_uint(v));  // v >= 0: bit order == float order
  }
}

// ze [16][256][1024] fp32 -> zebf (bf16) + zef (fp32) [16384][256]; fused anorm
__global__ __launch_bounds__(256) void k_cvt_ze(const float* __restrict__ ze,
                                                short* __restrict__ zebf,
                                                float* __restrict__ zef,
                                                float* __restrict__ an) {
  __shared__ float t[64][132];
  int tid = threadIdx.x;
  int p0 = blockIdx.x * 64;
  int b = p0 >> 10, hw0 = p0 & 1023;
  const float* src = ze + (size_t)b * 262144 + hw0;
  float apart = 0.f;
  for (int half = 0; half < 2; ++half) {
    if (half) __syncthreads();
    {
      int hw = tid & 63, cq = tid >> 6;
#pragma unroll
      for (int i = 0; i < 32; ++i) {
        int cl = i * 4 + cq;
        t[hw][cl] = src[(size_t)(half * 128 + cl) * 1024 + hw];
      }
    }
    __syncthreads();
    int r = tid >> 2, cg = tid & 3;
    float* fd = zef + (size_t)(p0 + r) * 256 + half * 128 + cg * 32;
    short* bd = zebf + (size_t)(p0 + r) * 256 + half * 128 + cg * 32;
#pragma unroll
    for (int s = 0; s < 8; ++s) {
      float4 v = *reinterpret_cast<const float4*>(&t[r][cg * 32 + s * 4]);
      *reinterpret_cast<float4*>(fd + s * 4) = v;
    }
#pragma unroll
    for (int s = 0; s < 4; ++s) {
      short8v v8;
#pragma unroll
      for (int e = 0; e < 8; ++e) v8[e] = f2bf(t[r][cg * 32 + s * 8 + e]);
      *reinterpret_cast<short8v*>(bd + s * 8) = v8;
    }
    if (tid < 64) {
      float a = np_pairwise128_sq(&t[tid][0], 1);
      apart = half ? __fadd_rn(apart, a) : a;
    }
  }
  if (tid < 64) an[p0 + tid] = apart;
}

// cb -> bf16; also init bmax
__global__ __launch_bounds__(256) void k_cvt_cb(const float* __restrict__ cb,
                                                short* __restrict__ cbbf,
                                                unsigned* __restrict__ bmaxu) {
  int tid = threadIdx.x;
  if (blockIdx.x == 0 && tid == 0) bmaxu[0] = 0u;
  size_t i = ((size_t)blockIdx.x * 256 + tid) * 8;
  float4 a = *reinterpret_cast<const float4*>(cb + i);
  float4 b = *reinterpret_cast<const float4*>(cb + i + 4);
  short8v v;
  v[0] = f2bf(a.x); v[1] = f2bf(a.y); v[2] = f2bf(a.z); v[3] = f2bf(a.w);
  v[4] = f2bf(b.x); v[5] = f2bf(b.y); v[6] = f2bf(b.z); v[7] = f2bf(b.w);
  *reinterpret_cast<short8v*>(cbbf + i) = v;
}

// A-in-register bf16 MFMA distance GEMM.
// Grid 256 = 32 pixel-chunks x 8 col-octants (octant ~ XCD: B-slice L2-local).
// Block: 8 waves; wave owns 64 pixels x full 64-col tile (A frags = 128 VGPR,
// pinned; acc 64 VGPR). B: 16 tiles of 64 cols x K256 (32 KB) streamed via
// LDS triple-buffer, counted vmcnt(4) (one tile always in flight), one raw
// s_barrier per iter. LDS bytes/MFMA = 256 -> MFMA-bound.
__global__ __launch_bounds__(512, 2) void k_gemm(const short* __restrict__ zebf,
                                                 const short* __restrict__ cbbf,
                                                 const float* __restrict__ bn,
                                                 float* __restrict__ wsmin) {
  __shared__ short lds[49152];  // 3 x 16384 shorts (32 KB each)
  int tid = threadIdx.x;
  int lane = tid & 63, w = tid >> 6;
  int g = lane >> 4, r16 = lane & 15;
  int oct = blockIdx.x & 7, chunk = blockIdx.x >> 3;
  int p0 = chunk * 512;
  int ncol0 = oct * 1024;
  const float* bnp = bn + ncol0;

  // ---- A fragments: pinned in registers (wave's 64 pixels x K256)
  short8v af[4][8];
  {
    const short* Arow = zebf + (size_t)(p0 + w * 64) * 256;
#pragma unroll
    for (int rf = 0; rf < 4; ++rf)
#pragma unroll
      for (int ks = 0; ks < 8; ++ks)
        af[rf][ks] = *reinterpret_cast<const short8v*>(
            Arow + (rf * 16 + r16) * 256 + (ks * 4 + g) * 8);
  }

  // ---- stage B tiles 0,1 (pre-swizzled source, linear LDS dest)
#define STAGE(t, boff)                                                         \
  {                                                                            \
    const short* src_ = cbbf + (size_t)(ncol0 + (t) * 64) * 256;               \
    _Pragma("unroll") for (int s = 0; s < 4; ++s) {                            \
      int cid_ = tid + s * 512;                                                \
      int col_ = cid_ >> 5, x_ = cid_ & 31;                                    \
      gll16(src_ + (size_t)col_ * 256 + (x_ ^ (col_ & 7)) * 8,                 \
            &lds[(boff) + cid_ * 8]);                                          \
    }                                                                          \
  }
  STAGE(0, 0)
  STAGE(1, 16384)
  // drain A(32) + B0(4), leave B1(4) in flight
  asm volatile("s_waitcnt vmcnt(4)" ::: "memory");
  __builtin_amdgcn_s_barrier();

  int bA = 0, bB = 16384, bC = 32768;
  for (int t = 0; t < 16; ++t) {
    float bnv[4];
#pragma unroll
    for (int cf = 0; cf < 4; ++cf) bnv[cf] = bnp[t * 64 + cf * 16 + r16];
    if (t < 14) STAGE(t + 2, bC)

    floatx4 acc[4][4];
#pragma unroll
    for (int rf = 0; rf < 4; ++rf)
#pragma unroll
      for (int cf = 0; cf < 4; ++cf) acc[rf][cf] = floatx4{0.f, 0.f, 0.f, 0.f};

    __builtin_amdgcn_s_setprio(1);
#pragma unroll
    for (int ks = 0; ks < 8; ++ks) {  // k-ascending: bit-identical chains
      short8v bf[4];
#pragma unroll
      for (int cf = 0; cf < 4; ++cf) {
        int col = cf * 16 + r16;
        bf[cf] = *reinterpret_cast<const short8v*>(
            &lds[bA + col * 256 + (((ks * 4 + g) ^ (col & 7)) * 8)]);
      }
#pragma unroll
      for (int rf = 0; rf < 4; ++rf)
#pragma unroll
        for (int cf = 0; cf < 4; ++cf)
          acc[rf][cf] = __builtin_amdgcn_mfma_f32_16x16x32_bf16(
              af[rf][ks], bf[cf], acc[rf][cf], 0, 0, 0);
    }
    __builtin_amdgcn_s_setprio(0);

    // counted wait: drain B(t+1) + bnv(t); keep B(t+2) in flight
    if (t < 14)
      asm volatile("s_waitcnt vmcnt(4)" ::: "memory");
    else
      asm volatile("s_waitcnt vmcnt(0)" ::: "memory");

    // per-pixel min over this tile's 64 cols
    float m[4][4];
#pragma unroll
    for (int rf = 0; rf < 4; ++rf)
#pragma unroll
      for (int rr = 0; rr < 4; ++rr) {
        float t0 = __builtin_fmaf(-2.0f, acc[rf][0][rr], bnv[0]);
        float t1 = __builtin_fmaf(-2.0f, acc[rf][1][rr], bnv[1]);
        float t2 = __builtin_fmaf(-2.0f, acc[rf][2][rr], bnv[2]);
        float t3 = __builtin_fmaf(-2.0f, acc[rf][3][rr], bnv[3]);
        m[rf][rr] = fminf(fminf(t0, t1), fminf(t2, t3));
      }
#pragma unroll
    for (int off = 1; off < 16; off <<= 1)
#pragma unroll
      for (int rf = 0; rf < 4; ++rf)
#pragma unroll
        for (int rr = 0; rr < 4; ++rr)
          m[rf][rr] = fminf(m[rf][rr], __shfl_xor(m[rf][rr], off, 16));
    if (r16 == 0) {
      float* wout = wsmin + (size_t)(oct * 16 + t) * NPIX + p0 + w * 64;
#pragma unroll
      for (int rf = 0; rf < 4; ++rf) {
        float4 v = make_float4(m[rf][0], m[rf][1], m[rf][2], m[rf][3]);
        *reinterpret_cast<float4*>(wout + rf * 16 + g * 4) = v;
      }
    }
    __builtin_amdgcn_s_barrier();
    int tmp = bA; bA = bB; bB = bC; bC = tmp;
  }
#undef STAGE
}

// per-pixel global min over 128 colblocks -> tau; init pk. No atomics.
__global__ __launch_bounds__(256) void k_tau(const float* __restrict__ wsmin,
                                             const float* __restrict__ an,
                                             const unsigned* __restrict__ bmaxu,
                                             float* __restrict__ tau,
                                             unsigned long long* __restrict__ pk) {
  __shared__ float sm[4][64];
  int tid = threadIdx.x;
  int px = tid & 63, q = tid >> 6;
  int p = blockIdx.x * 64 + px;
  float m0 = 3.4e38f, m1 = 3.4e38f, m2 = 3.4e38f, m3 = 3.4e38f;
#pragma unroll
  for (int i = 0; i < 8; ++i) {
    int c = q * 32 + i * 4;
    m0 = fminf(m0, wsmin[(size_t)c * NPIX + p]);
    m1 = fminf(m1, wsmin[(size_t)(c + 1) * NPIX + p]);
    m2 = fminf(m2, wsmin[(size_t)(c + 2) * NPIX + p]);
    m3 = fminf(m3, wsmin[(size_t)(c + 3) * NPIX + p]);
  }
  sm[q][px] = fminf(fminf(m0, m1), fminf(m2, m3));
  __syncthreads();
  if (tid < 64) {
    float m = fminf(fminf(sm[0][tid], sm[1][tid]), fminf(sm[2][tid], sm[3][tid]));
    float bmaxf = sqrtf(__uint_as_float(bmaxu[0]));
    tau[p] = m + 0.017f * sqrtf(an[p]) * bmaxf + 2e-4f;
    pk[p] = ~0ull;
  }
}

// per-colblock compaction of flagged pixels, ascending p, zero atomics.
__global__ __launch_bounds__(256) void k_compact(const float* __restrict__ wsmin,
                                                 const float* __restrict__ tau,
                                                 int* __restrict__ bcnt,
                                                 int* __restrict__ blist) {
  __shared__ int wbase[4];
  __shared__ int running;
  int c = blockIdx.x;
  const float* row = wsmin + (size_t)c * NPIX;
  int* dst = blist + (size_t)c * NPIX;
  int tid = threadIdx.x;
  int lane = tid & 63, wv = tid >> 6;
  if (tid == 0) running = 0;
  __syncthreads();
  for (int base = 0; base < NPIX; base += 256) {
    int p = base + tid;
    bool flag = row[p] <= tau[p];
    unsigned long long mask = __ballot(flag);
    int cnt = __popcll(mask);
    int pre = __popcll(mask & ((1ull << lane) - 1ull));
    if (lane == 0) wbase[wv] = cnt;
    __syncthreads();
    if (tid == 0) {
      int r = running;
#pragma unroll
      for (int w2 = 0; w2 < 4; ++w2) {
        int t = wbase[w2];
        wbase[w2] = r;
        r += t;
      }
      running = r;
    }
    __syncthreads();
    if (flag) dst[wbase[wv] + pre] = p;
    __syncthreads();
  }
  if (tid == 0) bcnt[c] = running;
}

// bucketed exact fp32 rescore, persistent grid.
__global__ __launch_bounds__(256) void k_rescore_b(
    const float* __restrict__ zef, const float* __restrict__ cb,
    const float* __restrict__ an, const float* __restrict__ bn,
    const int* __restrict__ bcnt, const int* __restrict__ blist,
    unsigned long long* __restrict__ pk) {
  __shared__ float cst[256][64];
  int tid = threadIdx.x;
  int lane = tid & 63, wv = tid >> 6;
  for (int id = blockIdx.x; id < 128 * 128; id += 512) {
    int c = id & 127;
    int chunk = id >> 7;
    int n = bcnt[c];
    int base = chunk * CHUNK;
    if (base >= n) continue;
    int cnt_here = min(CHUNK, n - base);
    __syncthreads();
    {
      int j = tid >> 2, kq = tid & 3;
      const float* src = cb + (size_t)(c * 64 + j) * 256 + kq * 64;
#pragma unroll
      for (int i = 0; i < 16; ++i) {
        float4 v = *reinterpret_cast<const float4*>(src + i * 4);
        int k = kq * 64 + i * 4;
        cst[k][j] = v.x; cst[k + 1][j] = v.y;
        cst[k + 2][j] = v.z; cst[k + 3][j] = v.w;
      }
    }
    __syncthreads();
    int j_global = c * 64 + lane;
    float bnj = bn[j_global];
    for (int g0 = wv * 4; g0 < cnt_here; g0 += 16) {
      int p[4];
      float4 z[4];
      float ap[4];
#pragma unroll
      for (int gi = 0; gi < 4; ++gi) {
        int idx = base + min(g0 + gi, cnt_here - 1);
        p[gi] = blist[(size_t)c * NPIX + idx];
        z[gi] = *reinterpret_cast<const float4*>(zef + (size_t)p[gi] * 256 +
                                                 lane * 4);
        ap[gi] = an[p[gi]];
      }
      float acc0 = 0.f, acc1 = 0.f, acc2 = 0.f, acc3 = 0.f;
#pragma unroll 8
      for (int k4 = 0; k4 < 64; ++k4) {
#pragma unroll
        for (int kk = 0; kk < 4; ++kk) {
          float cv = cst[k4 * 4 + kk][lane];
          float z0 = (kk == 0) ? z[0].x : (kk == 1) ? z[0].y : (kk == 2) ? z[0].z : z[0].w;
          float z1 = (kk == 0) ? z[1].x : (kk == 1) ? z[1].y : (kk == 2) ? z[1].z : z[1].w;
          float z2 = (kk == 0) ? z[2].x : (kk == 1) ? z[2].y : (kk == 2) ? z[2].z : z[2].w;
          float z3 = (kk == 0) ? z[3].x : (kk == 1) ? z[3].y : (kk == 2) ? z[3].z : z[3].w;
          acc0 = __builtin_fmaf(rl(z0, k4), cv, acc0);
          acc1 = __builtin_fmaf(rl(z1, k4), cv, acc1);
          acc2 = __builtin_fmaf(rl(z2, k4), cv, acc2);
          acc3 = __builtin_fmaf(rl(z3, k4), cv, acc3);
        }
      }
      float dv[4] = {acc0, acc1, acc2, acc3};
#pragma unroll
      for (int gi = 0; gi < 4; ++gi) {
        float d = __fsub_rn(__fadd_rn(ap[gi], bnj), 2.0f * dv[gi]);
        unsigned long long q = packdj(d, j_global);
#pragma unroll
        for (int off = 1; off < 64; off <<= 1) {
          unsigned long long q2 = __shfl_xor(q, off);
          q = q2 < q ? q2 : q;
        }
        if (lane == 0) atomicMin(&pk[p[gi]], q);
      }
    }
  }
}

__global__ __launch_bounds__(256) void k_gather(const float* __restrict__ ze,
                                                const float* __restrict__ cb,
                                                const unsigned long long* __restrict__ pk,
                                                float* __restrict__ out_zq,
                                                float* __restrict__ out_idx,
                                                float* __restrict__ part) {
  __shared__ float qrow[64][257];
  __shared__ int sidx[64];
  int tid = threadIdx.x;
  int p0 = blockIdx.x * 64;
  int b = p0 >> 10, hw0 = p0 & 1023;
  if (tid < 64) {
    int bi = (int)(unsigned int)(pk[p0 + tid] & 0xffffffffull);
    sidx[tid] = bi;
    out_idx[p0 + tid] = (float)bi;
  }
  __syncthreads();
  for (int r = 0; r < 64; ++r)
    qrow[r][tid] = cb[(size_t)sidx[r] * 256 + tid];
  __syncthreads();
  float lsum = 0.f;
  size_t zbase = (size_t)b * 262144 + hw0;
#pragma unroll 4
  for (int i = 0; i < 64; ++i) {
    int px = tid & 63;
    int c = i * 4 + (tid >> 6);
    float qv = qrow[px][c];
    size_t gi = zbase + (size_t)c * 1024 + px;
    float zev = ze[gi];
    out_zq[gi] = __fadd_rn(zev, __fsub_rn(qv, zev));
    float d = zev - qv;
    lsum = __builtin_fmaf(d, d, lsum);
  }
#pragma unroll
  for (int off = 32; off; off >>= 1) lsum += __shfl_xor(lsum, off, 64);
  __shared__ float wsum[4];
  if ((tid & 63) == 0) wsum[tid >> 6] = lsum;
  __syncthreads();
  if (tid == 0) part[blockIdx.x] = (wsum[0] + wsum[1]) + (wsum[2] + wsum[3]);
}

__global__ __launch_bounds__(256) void k_final(const float* __restrict__ part,
                                               float* __restrict__ out0) {
  int tid = threadIdx.x;
  float s = part[tid];
#pragma unroll
  for (int off = 32; off; off >>= 1) s += __shfl_xor(s, off, 64);
  __shared__ float wsum[4];
  if ((tid & 63) == 0) wsum[tid >> 6] = s;
  __syncthreads();
  if (tid == 0)
    out0[0] = 1.25f * ((wsum[0] + wsum[1]) + (wsum[2] + wsum[3])) / 4194304.0f;
}

extern "C" void kernel_launch(void* const* d_in, const int* in_sizes, int n_in,
                              void* d_out, int out_size, void* d_ws, size_t ws_size,
                              hipStream_t stream) {
  const float* ze = (const float*)d_in[0];
  const float* cb = (const float*)d_in[1];
  float* out = (float*)d_out;
  char* ws = (char*)d_ws;
  short* zebf = (short*)(ws + WS_ZEBF);
  short* cbbf = (short*)(ws + WS_CBBF);
  float* zef = (float*)(ws + WS_ZEF);
  float* bn = (float*)(ws + WS_BN);
  float* an = (float*)(ws + WS_AN);
  float* wsmin = (float*)(ws + WS_MIN);
  float* tau = (float*)(ws + WS_TAU);
  int* blist = (int*)(ws + WS_BLIST);
  int* bcnt = (int*)(ws + WS_BCNT);
  unsigned* bmaxu = (unsigned*)(ws + WS_BMAXU);
  unsigned long long* pk = (unsigned long long*)(ws + WS_PK);
  float* part = (float*)(ws + WS_PART);
  float* out_loss = out;
  float* out_zq = out + 1;
  float* out_idx = out + 1 + 4194304;

  k_cvt_ze<<<256, 256, 0, stream>>>(ze, zebf, zef, an);
  k_cvt_cb<<<1024, 256, 0, stream>>>(cb, cbbf, bmaxu);
  k_bnorm<<<128, 256, 0, stream>>>(cb, bn, bmaxu);
  k_gemm<<<256, 512, 0, stream>>>(zebf, cbbf, bn, wsmin);
  k_tau<<<256, 256, 0, stream>>>(wsmin, an, bmaxu, tau, pk);
  k_compact<<<128, 256, 0, stream>>>(wsmin, tau, bcnt, blist);
  k_rescore_b<<<512, 256, 0, stream>>>(zef, cb, an, bn, bcnt, blist, pk);
  k_gather<<<256, 256, 0, stream>>>(ze, cb, pk, out_zq, out_idx, part);
  k_final<<<1, 256, 0, stream>>>(part, out_loss);
}

// Round 10
// 221.186 us; speedup vs baseline: 1.6320x; 1.0130x over previous
//
#include <hip/hip_runtime.h>
#include <hip/hip_bf16.h>

#define NPIX 16384
#define NVOC 8192
#define CHUNK 128

typedef short short8v __attribute__((ext_vector_type(8)));
typedef float floatx4 __attribute__((ext_vector_type(4)));

// ---- ws layout (bytes) ----
// region A (0..8 MB): zebf(frag) during cvt/gemm -> blist after gemm -> part
#define WS_ZEBF   0u          // 16384*256 bf16 = 8388608 (dead after k_gemm)
#define WS_BLIST  0u          // 128*16384 i32 = 8388608 (alias, post-gemm)
#define WS_PART   0u          // 256 f32 (alias, post-rescore; blist dead)
// region B: cbbf during gemm -> pk/tau after gemm
#define WS_CBBF   8388608u    // 8192*256 bf16 = 4194304 (dead after k_gemm)
#define WS_PK     8388608u    // 16384 u64 = 131072 (alias, post-gemm)
#define WS_TAU    8519680u    // 16384 f32 = 65536 (alias, post-gemm)
// persistent
#define WS_ZEF    12582912u   // 16384*256 f32 = 16777216
#define WS_MIN    29360128u   // 128*16384 f32 = 8388608
#define WS_BN     37748736u   // 8192 f32
#define WS_AN     37781504u   // 16384 f32
#define WS_BCNT   37847040u   // 128 i32 (pad to 512)
#define WS_BMAXU  37847552u   // 1 u32 (pad)

__device__ __forceinline__ short f2bf(float v) {
  __bf16 h = (__bf16)v;
  return __builtin_bit_cast(short, h);
}

__device__ __forceinline__ float rl(float v, int l) {
  return __uint_as_float(__builtin_amdgcn_readlane(__float_as_uint(v), l));
}

__device__ __forceinline__ unsigned long long packdj(float d, int j) {
  return ((unsigned long long)__float_as_uint(d) << 32) | (unsigned int)j;
}

__device__ __forceinline__ void gll16(const void* g, void* l) {
  __builtin_amdgcn_global_load_lds(
      (const __attribute__((address_space(1))) void*)g,
      (__attribute__((address_space(3))) void*)l, 16, 0, 0);
}

// numpy pairwise-sum of 128 squares
__device__ __forceinline__ float np_pairwise128_sq(const float* x, int stride) {
  float r[8];
#pragma unroll
  for (int j = 0; j < 8; ++j) {
    float v = x[j * stride];
    r[j] = __fmul_rn(v, v);
  }
#pragma unroll
  for (int i = 1; i < 16; ++i) {
#pragma unroll
    for (int j = 0; j < 8; ++j) {
      float v = x[(i * 8 + j) * stride];
      r[j] = __fadd_rn(r[j], __fmul_rn(v, v));
    }
  }
  return __fadd_rn(__fadd_rn(__fadd_rn(r[0], r[1]), __fadd_rn(r[2], r[3])),
                   __fadd_rn(__fadd_rn(r[4], r[5]), __fadd_rn(r[6], r[7])));
}

// ||codebook_j||^2 (numpy order) + global max(bn) via atomicMax on bits
__global__ __launch_bounds__(256) void k_bnorm(const float* __restrict__ cb,
                                               float* __restrict__ bn,
                                               unsigned* __restrict__ bmaxu) {
  __shared__ float rows[64][257];
  int tid = threadIdx.x;
  int c0 = blockIdx.x * 64;
  for (int r = 0; r < 64; ++r)
    rows[r][tid] = cb[(size_t)(c0 + r) * 256 + tid];
  __syncthreads();
  if (tid < 64) {
    float a = np_pairwise128_sq(&rows[tid][0], 1);
    float b = np_pairwise128_sq(&rows[tid][128], 1);
    float v = __fadd_rn(a, b);
    bn[c0 + tid] = v;
    atomicMax(bmaxu, __float_as_uint(v));
  }
}

// ze [16][256][1024] fp32 -> zebf in MFMA-FRAGMENT order + zef (fp32) + an.
// Frag record: for pixel-group pg (16 px) and ks (k-chunk of 32), lane l holds
// 8 bf16 of pixel pg*16+(l&15), k = ks*32+(l>>4)*8+e, at offset
// ((pg*8+ks)*64+l)*8 shorts -> k_gemm's pixel-frag loads are 1KB coalesced.
__global__ __launch_bounds__(256) void k_cvt_ze(const float* __restrict__ ze,
                                                short* __restrict__ zebff,
                                                float* __restrict__ zef,
                                                float* __restrict__ an) {
  __shared__ float t[64][132];
  int tid = threadIdx.x;
  int p0 = blockIdx.x * 64;
  int b = p0 >> 10, hw0 = p0 & 1023;
  const float* src = ze + (size_t)b * 262144 + hw0;
  float apart = 0.f;
  for (int half = 0; half < 2; ++half) {
    if (half) __syncthreads();
    {
      int hw = tid & 63, cq = tid >> 6;
#pragma unroll
      for (int i = 0; i < 32; ++i) {
        int cl = i * 4 + cq;
        t[hw][cl] = src[(size_t)(half * 128 + cl) * 1024 + hw];
      }
    }
    __syncthreads();
    {
      int r = tid >> 2, cg = tid & 3;
      float* fd = zef + (size_t)(p0 + r) * 256 + half * 128 + cg * 32;
#pragma unroll
      for (int s = 0; s < 8; ++s) {
        float4 v = *reinterpret_cast<const float4*>(&t[r][cg * 32 + s * 4]);
        *reinterpret_cast<float4*>(fd + s * 4) = v;
      }
    }
    {
      int pg_l = tid >> 6, l = tid & 63;
      size_t pg = (size_t)(p0 >> 4) + pg_l;
      int lr = l & 15, lg = l >> 4;
#pragma unroll
      for (int kl = 0; kl < 4; ++kl) {
        int ks = half * 4 + kl;
        short8v v8;
#pragma unroll
        for (int e = 0; e < 8; ++e)
          v8[e] = f2bf(t[pg_l * 16 + lr][kl * 32 + lg * 8 + e]);
        *reinterpret_cast<short8v*>(zebff + (pg * 8 + ks) * 512 + l * 8) = v8;
      }
    }
    if (tid < 64) {
      float a = np_pairwise128_sq(&t[tid][0], 1);
      apart = half ? __fadd_rn(apart, a) : a;
    }
  }
  if (tid < 64) an[p0 + tid] = apart;
}

// cb -> bf16 row-major; also init bmax
__global__ __launch_bounds__(256) void k_cvt_cb(const float* __restrict__ cb,
                                                short* __restrict__ cbbf,
                                                unsigned* __restrict__ bmaxu) {
  int tid = threadIdx.x;
  if (blockIdx.x == 0 && tid == 0) bmaxu[0] = 0u;
  size_t i = ((size_t)blockIdx.x * 256 + tid) * 8;
  float4 a = *reinterpret_cast<const float4*>(cb + i);
  float4 b = *reinterpret_cast<const float4*>(cb + i + 4);
  short8v v;
  v[0] = f2bf(a.x); v[1] = f2bf(a.y); v[2] = f2bf(a.z); v[3] = f2bf(a.w);
  v[4] = f2bf(b.x); v[5] = f2bf(b.y); v[6] = f2bf(b.z); v[7] = f2bf(b.w);
  *reinterpret_cast<short8v*>(cbbf + i) = v;
}

// Swapped-operand bf16 MFMA distance GEMM.
// Grid 256 = 32 px-chunks x 8 octants (oct = blockIdx&7 ~ XCD, B L2-local).
// Block: 4 waves (256 thr), 1/SIMD. Wave owns 128 px x 64-col tile:
// pixel frags pinned (256 VGPR), codebook tile from LDS (A-operand).
// D[code][pixel] -> per-pixel colmin is in-lane VALU + 2 shuffles.
// 16 tiles, triple-buffered staging, exact counted vmcnt, 1 barrier/iter.
__global__ __launch_bounds__(256, 1) void k_gemm(const short* __restrict__ zebff,
                                                 const short* __restrict__ cbbf,
                                                 const float* __restrict__ bn,
                                                 float* __restrict__ wsmin) {
  __shared__ short lds[49152];   // 3 x 32 KB B-tile buffers
  __shared__ float bnlds[1024];  // octant bn
  int tid = threadIdx.x;
  int lane = tid & 63, w = tid >> 6;
  int g = lane >> 4, r16 = lane & 15;
  int oct = blockIdx.x & 7, chunk = blockIdx.x >> 3;
  int p0 = chunk * 512;
  int ncol0 = oct * 1024;

  // pixel fragments: 8 pf x 8 ks, coalesced 1KB loads from frag-ordered zebff
  short8v pix[8][8];
  {
    const short* base = zebff + ((size_t)(p0 >> 4) + w * 8) * 4096 + lane * 8;
#pragma unroll
    for (int pf = 0; pf < 8; ++pf)
#pragma unroll
      for (int ks = 0; ks < 8; ++ks)
        pix[pf][ks] =
            *reinterpret_cast<const short8v*>(base + pf * 4096 + ks * 512);
  }
  gll16(bn + ncol0 + tid * 4, &bnlds[tid * 4]);

#define STAGE(t, boff)                                                         \
  {                                                                            \
    const short* src_ = cbbf + (size_t)(ncol0 + (t) * 64) * 256;               \
    _Pragma("unroll") for (int s = 0; s < 8; ++s) {                            \
      int cid_ = tid + s * 256;                                                \
      int col_ = cid_ >> 5, x_ = cid_ & 31;                                    \
      gll16(src_ + (size_t)col_ * 256 + (x_ ^ (col_ & 7)) * 8,                 \
            &lds[(boff) + cid_ * 8]);                                          \
    }                                                                          \
  }
  STAGE(0, 0)
  STAGE(1, 16384)

  float* wbase = wsmin + (size_t)(oct * 16) * NPIX + p0 + w * 128 + r16;

#define ITERBODY(t, bA, bC, DOSTAGE, VMC)                                      \
  {                                                                            \
    asm volatile("s_waitcnt vmcnt(" VMC ")" ::: "memory");                     \
    __builtin_amdgcn_s_barrier();                                              \
    if (DOSTAGE) STAGE((t) + 2, bC)                                            \
    float4 bnv[4];                                                             \
    _Pragma("unroll") for (int cf = 0; cf < 4; ++cf) bnv[cf] =                 \
        *reinterpret_cast<const float4*>(&bnlds[(t) * 64 + cf * 16 + g * 4]);  \
    floatx4 acc[4][8];                                                         \
    _Pragma("unroll") for (int cf = 0; cf < 4; ++cf)                           \
        _Pragma("unroll") for (int pf = 0; pf < 8; ++pf) acc[cf][pf] =         \
        floatx4{0.f, 0.f, 0.f, 0.f};                                           \
    _Pragma("unroll") for (int ks = 0; ks < 8; ++ks) {                         \
      short8v cfr[4];                                                          \
      _Pragma("unroll") for (int cf = 0; cf < 4; ++cf) cfr[cf] =               \
          *reinterpret_cast<const short8v*>(                                   \
              &lds[(bA) + (cf * 16 + r16) * 256 +                              \
                   (((ks) * 4 + g) ^ (r16 & 7)) * 8]);                         \
      _Pragma("unroll") for (int cf = 0; cf < 4; ++cf)                         \
          _Pragma("unroll") for (int pf = 0; pf < 8; ++pf) acc[cf][pf] =       \
          __builtin_amdgcn_mfma_f32_16x16x32_bf16(cfr[cf], pix[pf][ks],        \
                                                  acc[cf][pf], 0, 0, 0);       \
    }                                                                          \
    float pmin[8];                                                             \
    _Pragma("unroll") for (int pf = 0; pf < 8; ++pf) {                         \
      float m_ = 3.4e38f;                                                      \
      _Pragma("unroll") for (int cf = 0; cf < 4; ++cf)                         \
          _Pragma("unroll") for (int rr = 0; rr < 4; ++rr) m_ =                \
          fminf(m_, __builtin_fmaf(-2.0f, acc[cf][pf][rr], bnv[cf][rr]));      \
      m_ = fminf(m_, __shfl_xor(m_, 16));                                      \
      m_ = fminf(m_, __shfl_xor(m_, 32));                                      \
      pmin[pf] = m_;                                                           \
    }                                                                          \
    if (lane < 16) {                                                           \
      _Pragma("unroll") for (int pf = 0; pf < 8; ++pf)                         \
          wbase[(size_t)(t) * NPIX + pf * 16] = pmin[pf];                      \
    }                                                                          \
  }

  ITERBODY(0, 0, 32768, 1, "8")
  ITERBODY(1, 16384, 0, 1, "16")
#pragma unroll 1
  for (int u = 0; u < 4; ++u) {
    int t0 = 3 * u + 2;
    ITERBODY(t0, 32768, 16384, 1, "24")
    ITERBODY(t0 + 1, 0, 32768, 1, "24")
    ITERBODY(t0 + 2, 16384, 0, 1, "24")
  }
  ITERBODY(14, 32768, 0, 0, "24")
  ITERBODY(15, 0, 0, 0, "16")
#undef STAGE
#undef ITERBODY
}

// per-pixel global min over 128 colblocks -> tau; init pk. No atomics.
__global__ __launch_bounds__(256) void k_tau(const float* __restrict__ wsmin,
                                             const float* __restrict__ an,
                                             const unsigned* __restrict__ bmaxu,
                                             float* __restrict__ tau,
                                             unsigned long long* __restrict__ pk) {
  __shared__ float sm[4][64];
  int tid = threadIdx.x;
  int px = tid & 63, q = tid >> 6;
  int p = blockIdx.x * 64 + px;
  float m0 = 3.4e38f, m1 = 3.4e38f, m2 = 3.4e38f, m3 = 3.4e38f;
#pragma unroll
  for (int i = 0; i < 8; ++i) {
    int c = q * 32 + i * 4;
    m0 = fminf(m0, wsmin[(size_t)c * NPIX + p]);
    m1 = fminf(m1, wsmin[(size_t)(c + 1) * NPIX + p]);
    m2 = fminf(m2, wsmin[(size_t)(c + 2) * NPIX + p]);
    m3 = fminf(m3, wsmin[(size_t)(c + 3) * NPIX + p]);
  }
  sm[q][px] = fminf(fminf(m0, m1), fminf(m2, m3));
  __syncthreads();
  if (tid < 64) {
    float m = fminf(fminf(sm[0][tid], sm[1][tid]), fminf(sm[2][tid], sm[3][tid]));
    float bmaxf = sqrtf(__uint_as_float(bmaxu[0]));
    tau[p] = m + 0.017f * sqrtf(an[p]) * bmaxf + 2e-4f;
    pk[p] = ~0ull;
  }
}

// per-colblock compaction of flagged pixels, ascending p, zero atomics.
__global__ __launch_bounds__(256) void k_compact(const float* __restrict__ wsmin,
                                                 const float* __restrict__ tau,
                                                 int* __restrict__ bcnt,
                                                 int* __restrict__ blist) {
  __shared__ int wbase[4];
  __shared__ int running;
  int c = blockIdx.x;
  const float* row = wsmin + (size_t)c * NPIX;
  int* dst = blist + (size_t)c * NPIX;
  int tid = threadIdx.x;
  int lane = tid & 63, wv = tid >> 6;
  if (tid == 0) running = 0;
  __syncthreads();
  for (int base = 0; base < NPIX; base += 256) {
    int p = base + tid;
    bool flag = row[p] <= tau[p];
    unsigned long long mask = __ballot(flag);
    int cnt = __popcll(mask);
    int pre = __popcll(mask & ((1ull << lane) - 1ull));
    if (lane == 0) wbase[wv] = cnt;
    __syncthreads();
    if (tid == 0) {
      int r = running;
#pragma unroll
      for (int w2 = 0; w2 < 4; ++w2) {
        int t = wbase[w2];
        wbase[w2] = r;
        r += t;
      }
      running = r;
    }
    __syncthreads();
    if (flag) dst[wbase[wv] + pre] = p;
    __syncthreads();
  }
  if (tid == 0) bcnt[c] = running;
}

// bucketed exact fp32 rescore, persistent grid.
__global__ __launch_bounds__(256) void k_rescore_b(
    const float* __restrict__ zef, const float* __restrict__ cb,
    const float* __restrict__ an, const float* __restrict__ bn,
    const int* __restrict__ bcnt, const int* __restrict__ blist,
    unsigned long long* __restrict__ pk) {
  __shared__ float cst[256][64];
  int tid = threadIdx.x;
  int lane = tid & 63, wv = tid >> 6;
  for (int id = blockIdx.x; id < 128 * 128; id += 512) {
    int c = id & 127;
    int chunk = id >> 7;
    int n = bcnt[c];
    int base = chunk * CHUNK;
    if (base >= n) continue;
    int cnt_here = min(CHUNK, n - base);
    __syncthreads();
    {
      int j = tid >> 2, kq = tid & 3;
      const float* src = cb + (size_t)(c * 64 + j) * 256 + kq * 64;
#pragma unroll
      for (int i = 0; i < 16; ++i) {
        float4 v = *reinterpret_cast<const float4*>(src + i * 4);
        int k = kq * 64 + i * 4;
        cst[k][j] = v.x; cst[k + 1][j] = v.y;
        cst[k + 2][j] = v.z; cst[k + 3][j] = v.w;
      }
    }
    __syncthreads();
    int j_global = c * 64 + lane;
    float bnj = bn[j_global];
    for (int g0 = wv * 4; g0 < cnt_here; g0 += 16) {
      int p[4];
      float4 z[4];
      float ap[4];
#pragma unroll
      for (int gi = 0; gi < 4; ++gi) {
        int idx = base + min(g0 + gi, cnt_here - 1);
        p[gi] = blist[(size_t)c * NPIX + idx];
        z[gi] = *reinterpret_cast<const float4*>(zef + (size_t)p[gi] * 256 +
                                                 lane * 4);
        ap[gi] = an[p[gi]];
      }
      float acc0 = 0.f, acc1 = 0.f, acc2 = 0.f, acc3 = 0.f;
#pragma unroll 8
      for (int k4 = 0; k4 < 64; ++k4) {
#pragma unroll
        for (int kk = 0; kk < 4; ++kk) {
          float cv = cst[k4 * 4 + kk][lane];
          float z0 = (kk == 0) ? z[0].x : (kk == 1) ? z[0].y : (kk == 2) ? z[0].z : z[0].w;
          float z1 = (kk == 0) ? z[1].x : (kk == 1) ? z[1].y : (kk == 2) ? z[1].z : z[1].w;
          float z2 = (kk == 0) ? z[2].x : (kk == 1) ? z[2].y : (kk == 2) ? z[2].z : z[2].w;
          float z3 = (kk == 0) ? z[3].x : (kk == 1) ? z[3].y : (kk == 2) ? z[3].z : z[3].w;
          acc0 = __builtin_fmaf(rl(z0, k4), cv, acc0);
          acc1 = __builtin_fmaf(rl(z1, k4), cv, acc1);
          acc2 = __builtin_fmaf(rl(z2, k4), cv, acc2);
          acc3 = __builtin_fmaf(rl(z3, k4), cv, acc3);
        }
      }
      float dv[4] = {acc0, acc1, acc2, acc3};
#pragma unroll
      for (int gi = 0; gi < 4; ++gi) {
        float d = __fsub_rn(__fadd_rn(ap[gi], bnj), 2.0f * dv[gi]);
        unsigned long long q = packdj(d, j_global);
#pragma unroll
        for (int off = 1; off < 64; off <<= 1) {
          unsigned long long q2 = __shfl_xor(q, off);
          q = q2 < q ? q2 : q;
        }
        if (lane == 0) atomicMin(&pk[p[gi]], q);
      }
    }
  }
}

__global__ __launch_bounds__(256) void k_gather(const float* __restrict__ ze,
                                                const float* __restrict__ cb,
                                                const unsigned long long* __restrict__ pk,
                                                float* __restrict__ out_zq,
                                                float* __restrict__ out_idx,
                                                float* __restrict__ part) {
  __shared__ float qrow[64][257];
  __shared__ int sidx[64];
  int tid = threadIdx.x;
  int p0 = blockIdx.x * 64;
  int b = p0 >> 10, hw0 = p0 & 1023;
  if (tid < 64) {
    int bi = (int)(unsigned int)(pk[p0 + tid] & 0xffffffffull);
    sidx[tid] = bi;
    out_idx[p0 + tid] = (float)bi;
  }
  __syncthreads();
  for (int r = 0; r < 64; ++r)
    qrow[r][tid] = cb[(size_t)sidx[r] * 256 + tid];
  __syncthreads();
  float lsum = 0.f;
  size_t zbase = (size_t)b * 262144 + hw0;
#pragma unroll 4
  for (int i = 0; i < 64; ++i) {
    int px = tid & 63;
    int c = i * 4 + (tid >> 6);
    float qv = qrow[px][c];
    size_t gi = zbase + (size_t)c * 1024 + px;
    float zev = ze[gi];
    out_zq[gi] = __fadd_rn(zev, __fsub_rn(qv, zev));
    float d = zev - qv;
    lsum = __builtin_fmaf(d, d, lsum);
  }
#pragma unroll
  for (int off = 32; off; off >>= 1) lsum += __shfl_xor(lsum, off, 64);
  __shared__ float wsum[4];
  if ((tid & 63) == 0) wsum[tid >> 6] = lsum;
  __syncthreads();
  if (tid == 0) part[blockIdx.x] = (wsum[0] + wsum[1]) + (wsum[2] + wsum[3]);
}

__global__ __launch_bounds__(256) void k_final(const float* __restrict__ part,
                                               float* __restrict__ out0) {
  int tid = threadIdx.x;
  float s = part[tid];
#pragma unroll
  for (int off = 32; off; off >>= 1) s += __shfl_xor(s, off, 64);
  __shared__ float wsum[4];
  if ((tid & 63) == 0) wsum[tid >> 6] = s;
  __syncthreads();
  if (tid == 0)
    out0[0] = 1.25f * ((wsum[0] + wsum[1]) + (wsum[2] + wsum[3])) / 4194304.0f;
}

extern "C" void kernel_launch(void* const* d_in, const int* in_sizes, int n_in,
                              void* d_out, int out_size, void* d_ws, size_t ws_size,
                              hipStream_t stream) {
  const float* ze = (const float*)d_in[0];
  const float* cb = (const float*)d_in[1];
  float* out = (float*)d_out;
  char* ws = (char*)d_ws;
  short* zebff = (short*)(ws + WS_ZEBF);
  short* cbbf = (short*)(ws + WS_CBBF);
  float* zef = (float*)(ws + WS_ZEF);
  float* bn = (float*)(ws + WS_BN);
  float* an = (float*)(ws + WS_AN);
  float* wsmin = (float*)(ws + WS_MIN);
  float* tau = (float*)(ws + WS_TAU);
  int* blist = (int*)(ws + WS_BLIST);
  int* bcnt = (int*)(ws + WS_BCNT);
  unsigned* bmaxu = (unsigned*)(ws + WS_BMAXU);
  unsigned long long* pk = (unsigned long long*)(ws + WS_PK);
  float* part = (float*)(ws + WS_PART);
  float* out_loss = out;
  float* out_zq = out + 1;
  float* out_idx = out + 1 + 4194304;

  k_cvt_ze<<<256, 256, 0, stream>>>(ze, zebff, zef, an);
  k_cvt_cb<<<1024, 256, 0, stream>>>(cb, cbbf, bmaxu);
  k_bnorm<<<128, 256, 0, stream>>>(cb, bn, bmaxu);
  k_gemm<<<256, 256, 0, stream>>>(zebff, cbbf, bn, wsmin);
  k_tau<<<256, 256, 0, stream>>>(wsmin, an, bmaxu, tau, pk);
  k_compact<<<128, 256, 0, stream>>>(wsmin, tau, bcnt, blist);
  k_rescore_b<<<512, 256, 0, stream>>>(zef, cb, an, bn, bcnt, blist, pk);
  k_gather<<<256, 256, 0, stream>>>(ze, cb, pk, out_zq, out_idx, part);
  k_final<<<1, 256, 0, stream>>>(part, out_loss);
}

// Round 11
// 195.468 us; speedup vs baseline: 1.8468x; 1.1316x over previous
//
#include <hip/hip_runtime.h>
#include <hip/hip_bf16.h>

#define NPIX 16384
#define NVOC 8192
#define CHUNK 128

typedef short short8v __attribute__((ext_vector_type(8)));
typedef float floatx4 __attribute__((ext_vector_type(4)));

// ---- ws layout (bytes) ----
// region A (0..8 MB): zebf(frag) during cvt/gemm -> blist after gemm -> part
#define WS_ZEBF   0u          // 16384*256 bf16 = 8388608 (dead after k_gemm)
#define WS_BLIST  0u          // 128*16384 i32 = 8388608 (alias, post-gemm)
#define WS_PART   0u          // 256 f32 (alias, post-rescore; blist dead)
// region B: cbbft during gemm -> pk/tau after gemm
#define WS_CBBF   8388608u    // 8192*256 bf16 = 4194304 (dead after k_gemm)
#define WS_PK     8388608u    // 16384 u64 = 131072 (alias, post-gemm)
#define WS_TAU    8519680u    // 16384 f32 = 65536 (alias, post-gemm)
// persistent
#define WS_ZEF    12582912u   // 16384*256 f32 = 16777216
#define WS_MIN    29360128u   // 128*16384 f32 = 8388608
#define WS_BN     37748736u   // 8192 f32
#define WS_AN     37781504u   // 16384 f32
#define WS_BCNT   37847040u   // 128 i32 (pad to 512)
#define WS_BMAXU  37847552u   // 1 u32 (pad)

__device__ __forceinline__ short f2bf(float v) {
  __bf16 h = (__bf16)v;
  return __builtin_bit_cast(short, h);
}

__device__ __forceinline__ float rl(float v, int l) {
  return __uint_as_float(__builtin_amdgcn_readlane(__float_as_uint(v), l));
}

__device__ __forceinline__ unsigned long long packdj(float d, int j) {
  return ((unsigned long long)__float_as_uint(d) << 32) | (unsigned int)j;
}

__device__ __forceinline__ void gll16(const void* g, void* l) {
  __builtin_amdgcn_global_load_lds(
      (const __attribute__((address_space(1))) void*)g,
      (__attribute__((address_space(3))) void*)l, 16, 0, 0);
}

// numpy pairwise-sum of 128 squares
__device__ __forceinline__ float np_pairwise128_sq(const float* x, int stride) {
  float r[8];
#pragma unroll
  for (int j = 0; j < 8; ++j) {
    float v = x[j * stride];
    r[j] = __fmul_rn(v, v);
  }
#pragma unroll
  for (int i = 1; i < 16; ++i) {
#pragma unroll
    for (int j = 0; j < 8; ++j) {
      float v = x[(i * 8 + j) * stride];
      r[j] = __fadd_rn(r[j], __fmul_rn(v, v));
    }
  }
  return __fadd_rn(__fadd_rn(__fadd_rn(r[0], r[1]), __fadd_rn(r[2], r[3])),
                   __fadd_rn(__fadd_rn(r[4], r[5]), __fadd_rn(r[6], r[7])));
}

// ||codebook_j||^2 (numpy order) + global max(bn) via atomicMax on bits
__global__ __launch_bounds__(256) void k_bnorm(const float* __restrict__ cb,
                                               float* __restrict__ bn,
                                               unsigned* __restrict__ bmaxu) {
  __shared__ float rows[64][257];
  int tid = threadIdx.x;
  int c0 = blockIdx.x * 64;
  for (int r = 0; r < 64; ++r)
    rows[r][tid] = cb[(size_t)(c0 + r) * 256 + tid];
  __syncthreads();
  if (tid < 64) {
    float a = np_pairwise128_sq(&rows[tid][0], 1);
    float b = np_pairwise128_sq(&rows[tid][128], 1);
    float v = __fadd_rn(a, b);
    bn[c0 + tid] = v;
    atomicMax(bmaxu, __float_as_uint(v));
  }
}

// ze [16][256][1024] fp32 -> zebf in MFMA-FRAGMENT order + zef (fp32) + an.
__global__ __launch_bounds__(256) void k_cvt_ze(const float* __restrict__ ze,
                                                short* __restrict__ zebff,
                                                float* __restrict__ zef,
                                                float* __restrict__ an) {
  __shared__ float t[64][132];
  int tid = threadIdx.x;
  int p0 = blockIdx.x * 64;
  int b = p0 >> 10, hw0 = p0 & 1023;
  const float* src = ze + (size_t)b * 262144 + hw0;
  float apart = 0.f;
  for (int half = 0; half < 2; ++half) {
    if (half) __syncthreads();
    {
      int hw = tid & 63, cq = tid >> 6;
#pragma unroll
      for (int i = 0; i < 32; ++i) {
        int cl = i * 4 + cq;
        t[hw][cl] = src[(size_t)(half * 128 + cl) * 1024 + hw];
      }
    }
    __syncthreads();
    {
      int r = tid >> 2, cg = tid & 3;
      float* fd = zef + (size_t)(p0 + r) * 256 + half * 128 + cg * 32;
#pragma unroll
      for (int s = 0; s < 8; ++s) {
        float4 v = *reinterpret_cast<const float4*>(&t[r][cg * 32 + s * 4]);
        *reinterpret_cast<float4*>(fd + s * 4) = v;
      }
    }
    {
      int pg_l = tid >> 6, l = tid & 63;
      size_t pg = (size_t)(p0 >> 4) + pg_l;
      int lr = l & 15, lg = l >> 4;
#pragma unroll
      for (int kl = 0; kl < 4; ++kl) {
        int ks = half * 4 + kl;
        short8v v8;
#pragma unroll
        for (int e = 0; e < 8; ++e)
          v8[e] = f2bf(t[pg_l * 16 + lr][kl * 32 + lg * 8 + e]);
        *reinterpret_cast<short8v*>(zebff + (pg * 8 + ks) * 512 + l * 8) = v8;
      }
    }
    if (tid < 64) {
      float a = np_pairwise128_sq(&t[tid][0], 1);
      apart = half ? __fadd_rn(apart, a) : a;
    }
  }
  if (tid < 64) an[p0 + tid] = apart;
}

// cb -> bf16 in per-tile K-MAJOR layout: tile tt (64 cols), record cid:
// kc = cid>>6, col = cid&63 -> 8 bf16 of code tt*64+col, k=kc*8..kc*8+7 at
// cbbft[tt*16384 + cid*8]. Staging in k_gemm becomes a linear 32KB copy and
// LDS reads are bank-conflict-free. One block per tile (128 blocks).
__global__ __launch_bounds__(256) void k_cvt_cb(const float* __restrict__ cb,
                                                short* __restrict__ cbbft,
                                                unsigned* __restrict__ bmaxu) {
  __shared__ short t[64][264];
  int tid = threadIdx.x;
  if (blockIdx.x == 0 && tid == 0) bmaxu[0] = 0u;
  int j0 = blockIdx.x * 64;
  {
    int col = tid >> 2, q = tid & 3;
    const float* src = cb + (size_t)(j0 + col) * 256 + q * 64;
#pragma unroll
    for (int i = 0; i < 8; ++i) {
      float4 a = *reinterpret_cast<const float4*>(src + i * 8);
      float4 b = *reinterpret_cast<const float4*>(src + i * 8 + 4);
      short8v v;
      v[0] = f2bf(a.x); v[1] = f2bf(a.y); v[2] = f2bf(a.z); v[3] = f2bf(a.w);
      v[4] = f2bf(b.x); v[5] = f2bf(b.y); v[6] = f2bf(b.z); v[7] = f2bf(b.w);
      *reinterpret_cast<short8v*>(&t[col][q * 64 + i * 8]) = v;
    }
  }
  __syncthreads();
  short* dst = cbbft + (size_t)blockIdx.x * 16384;
#pragma unroll
  for (int s = 0; s < 8; ++s) {
    int cid = tid + s * 256;
    int kc = cid >> 6, c2 = cid & 63;
    short8v v = *reinterpret_cast<const short8v*>(&t[c2][kc * 8]);
    *reinterpret_cast<short8v*>(dst + cid * 8) = v;
  }
}

// Swapped-operand bf16 MFMA distance GEMM, 2 blocks/CU.
// Grid 512 = 64 px-chunks x 8 octants (oct ~ XCD, B-slice L2-local).
// Block: 4 waves (256 thr); wave owns 64 px x 64-col tile. Pixel frags pinned
// (128 VGPR); codebook tile (k-major, conflict-free) from LDS double-buffer
// (64KB + 4KB bn = 68KB -> 2 blocks/CU -> 2 waves/SIMD for latency hiding).
__global__ __launch_bounds__(256, 2) void k_gemm(const short* __restrict__ zebff,
                                                 const short* __restrict__ cbbft,
                                                 const float* __restrict__ bn,
                                                 float* __restrict__ wsmin) {
  __shared__ short lds[32768];   // 2 x 32 KB B-tile buffers
  __shared__ float bnlds[1024];  // octant bn
  int tid = threadIdx.x;
  int lane = tid & 63, w = tid >> 6;
  int g = lane >> 4, r16 = lane & 15;
  int oct = blockIdx.x & 7, chunk = blockIdx.x >> 3;
  int p0 = chunk * 256;
  int ncol0 = oct * 1024;

  // pixel fragments: 4 pf x 8 ks, coalesced 1KB loads from frag-ordered zebff
  short8v pix[4][8];
  {
    const short* base = zebff + ((size_t)(p0 >> 4) + w * 4) * 4096 + lane * 8;
#pragma unroll
    for (int pf = 0; pf < 4; ++pf)
#pragma unroll
      for (int ks = 0; ks < 8; ++ks)
        pix[pf][ks] =
            *reinterpret_cast<const short8v*>(base + pf * 4096 + ks * 512);
  }
  gll16(bn + ncol0 + tid * 4, &bnlds[tid * 4]);

#define STAGE(t, boff)                                                         \
  {                                                                            \
    const short* src_ = cbbft + (size_t)(oct * 16 + (t)) * 16384;              \
    _Pragma("unroll") for (int s = 0; s < 8; ++s) {                            \
      int cid_ = tid + s * 256;                                                \
      gll16(src_ + cid_ * 8, &lds[(boff) + cid_ * 8]);                         \
    }                                                                          \
  }
  STAGE(0, 0)
  asm volatile("s_waitcnt vmcnt(0)" ::: "memory");
  __builtin_amdgcn_s_barrier();

  float* wbase = wsmin + (size_t)(oct * 16) * NPIX + p0 + w * 64 + r16;

  for (int t = 0; t < 16; ++t) {
    int bA = (t & 1) * 16384;
    int bC = bA ^ 16384;
    if (t < 15) STAGE(t + 1, bC)
    float4 bnv[4];
#pragma unroll
    for (int cf = 0; cf < 4; ++cf)
      bnv[cf] =
          *reinterpret_cast<const float4*>(&bnlds[t * 64 + cf * 16 + g * 4]);
    floatx4 acc[4][4];
#pragma unroll
    for (int cf = 0; cf < 4; ++cf)
#pragma unroll
      for (int pf = 0; pf < 4; ++pf) acc[cf][pf] = floatx4{0.f, 0.f, 0.f, 0.f};
    __builtin_amdgcn_s_setprio(1);
#pragma unroll
    for (int ks = 0; ks < 8; ++ks) {  // k-ascending: bit-identical chains
      short8v cfr[4];
#pragma unroll
      for (int cf = 0; cf < 4; ++cf)
        cfr[cf] = *reinterpret_cast<const short8v*>(
            &lds[bA + (((ks * 4 + g) * 64) + cf * 16 + r16) * 8]);
#pragma unroll
      for (int cf = 0; cf < 4; ++cf)
#pragma unroll
        for (int pf = 0; pf < 4; ++pf)
          acc[cf][pf] = __builtin_amdgcn_mfma_f32_16x16x32_bf16(
              cfr[cf], pix[pf][ks], acc[cf][pf], 0, 0, 0);
    }
    __builtin_amdgcn_s_setprio(0);
    // per-pixel min over this tile's 64 codes: in-lane 16 + 2 shuffles
    float pmin[4];
#pragma unroll
    for (int pf = 0; pf < 4; ++pf) {
      float m_ = 3.4e38f;
#pragma unroll
      for (int cf = 0; cf < 4; ++cf)
#pragma unroll
        for (int rr = 0; rr < 4; ++rr)
          m_ = fminf(m_, __builtin_fmaf(-2.0f, acc[cf][pf][rr], bnv[cf][rr]));
      m_ = fminf(m_, __shfl_xor(m_, 16));
      m_ = fminf(m_, __shfl_xor(m_, 32));
      pmin[pf] = m_;
    }
    if (lane < 16) {
#pragma unroll
      for (int pf = 0; pf < 4; ++pf)
        wbase[(size_t)t * NPIX + pf * 16] = pmin[pf];
    }
    asm volatile("s_waitcnt vmcnt(0)" ::: "memory");
    __builtin_amdgcn_s_barrier();
  }
#undef STAGE
}

// per-pixel global min over 128 colblocks -> tau; init pk. No atomics.
__global__ __launch_bounds__(256) void k_tau(const float* __restrict__ wsmin,
                                             const float* __restrict__ an,
                                             const unsigned* __restrict__ bmaxu,
                                             float* __restrict__ tau,
                                             unsigned long long* __restrict__ pk) {
  __shared__ float sm[4][64];
  int tid = threadIdx.x;
  int px = tid & 63, q = tid >> 6;
  int p = blockIdx.x * 64 + px;
  float m0 = 3.4e38f, m1 = 3.4e38f, m2 = 3.4e38f, m3 = 3.4e38f;
#pragma unroll
  for (int i = 0; i < 8; ++i) {
    int c = q * 32 + i * 4;
    m0 = fminf(m0, wsmin[(size_t)c * NPIX + p]);
    m1 = fminf(m1, wsmin[(size_t)(c + 1) * NPIX + p]);
    m2 = fminf(m2, wsmin[(size_t)(c + 2) * NPIX + p]);
    m3 = fminf(m3, wsmin[(size_t)(c + 3) * NPIX + p]);
  }
  sm[q][px] = fminf(fminf(m0, m1), fminf(m2, m3));
  __syncthreads();
  if (tid < 64) {
    float m = fminf(fminf(sm[0][tid], sm[1][tid]), fminf(sm[2][tid], sm[3][tid]));
    float bmaxf = sqrtf(__uint_as_float(bmaxu[0]));
    tau[p] = m + 0.017f * sqrtf(an[p]) * bmaxf + 2e-4f;
    pk[p] = ~0ull;
  }
}

// per-colblock compaction of flagged pixels, ascending p, zero atomics.
__global__ __launch_bounds__(256) void k_compact(const float* __restrict__ wsmin,
                                                 const float* __restrict__ tau,
                                                 int* __restrict__ bcnt,
                                                 int* __restrict__ blist) {
  __shared__ int wbase[4];
  __shared__ int running;
  int c = blockIdx.x;
  const float* row = wsmin + (size_t)c * NPIX;
  int* dst = blist + (size_t)c * NPIX;
  int tid = threadIdx.x;
  int lane = tid & 63, wv = tid >> 6;
  if (tid == 0) running = 0;
  __syncthreads();
  for (int base = 0; base < NPIX; base += 256) {
    int p = base + tid;
    bool flag = row[p] <= tau[p];
    unsigned long long mask = __ballot(flag);
    int cnt = __popcll(mask);
    int pre = __popcll(mask & ((1ull << lane) - 1ull));
    if (lane == 0) wbase[wv] = cnt;
    __syncthreads();
    if (tid == 0) {
      int r = running;
#pragma unroll
      for (int w2 = 0; w2 < 4; ++w2) {
        int t = wbase[w2];
        wbase[w2] = r;
        r += t;
      }
      running = r;
    }
    __syncthreads();
    if (flag) dst[wbase[wv] + pre] = p;
    __syncthreads();
  }
  if (tid == 0) bcnt[c] = running;
}

// bucketed exact fp32 rescore, persistent grid.
__global__ __launch_bounds__(256) void k_rescore_b(
    const float* __restrict__ zef, const float* __restrict__ cb,
    const float* __restrict__ an, const float* __restrict__ bn,
    const int* __restrict__ bcnt, const int* __restrict__ blist,
    unsigned long long* __restrict__ pk) {
  __shared__ float cst[256][64];
  int tid = threadIdx.x;
  int lane = tid & 63, wv = tid >> 6;
  for (int id = blockIdx.x; id < 128 * 128; id += 512) {
    int c = id & 127;
    int chunk = id >> 7;
    int n = bcnt[c];
    int base = chunk * CHUNK;
    if (base >= n) continue;
    int cnt_here = min(CHUNK, n - base);
    __syncthreads();
    {
      int j = tid >> 2, kq = tid & 3;
      const float* src = cb + (size_t)(c * 64 + j) * 256 + kq * 64;
#pragma unroll
      for (int i = 0; i < 16; ++i) {
        float4 v = *reinterpret_cast<const float4*>(src + i * 4);
        int k = kq * 64 + i * 4;
        cst[k][j] = v.x; cst[k + 1][j] = v.y;
        cst[k + 2][j] = v.z; cst[k + 3][j] = v.w;
      }
    }
    __syncthreads();
    int j_global = c * 64 + lane;
    float bnj = bn[j_global];
    for (int g0 = wv * 4; g0 < cnt_here; g0 += 16) {
      int p[4];
      float4 z[4];
      float ap[4];
#pragma unroll
      for (int gi = 0; gi < 4; ++gi) {
        int idx = base + min(g0 + gi, cnt_here - 1);
        p[gi] = blist[(size_t)c * NPIX + idx];
        z[gi] = *reinterpret_cast<const float4*>(zef + (size_t)p[gi] * 256 +
                                                 lane * 4);
        ap[gi] = an[p[gi]];
      }
      float acc0 = 0.f, acc1 = 0.f, acc2 = 0.f, acc3 = 0.f;
#pragma unroll 8
      for (int k4 = 0; k4 < 64; ++k4) {
#pragma unroll
        for (int kk = 0; kk < 4; ++kk) {
          float cv = cst[k4 * 4 + kk][lane];
          float z0 = (kk == 0) ? z[0].x : (kk == 1) ? z[0].y : (kk == 2) ? z[0].z : z[0].w;
          float z1 = (kk == 0) ? z[1].x : (kk == 1) ? z[1].y : (kk == 2) ? z[1].z : z[1].w;
          float z2 = (kk == 0) ? z[2].x : (kk == 1) ? z[2].y : (kk == 2) ? z[2].z : z[2].w;
          float z3 = (kk == 0) ? z[3].x : (kk == 1) ? z[3].y : (kk == 2) ? z[3].z : z[3].w;
          acc0 = __builtin_fmaf(rl(z0, k4), cv, acc0);
          acc1 = __builtin_fmaf(rl(z1, k4), cv, acc1);
          acc2 = __builtin_fmaf(rl(z2, k4), cv, acc2);
          acc3 = __builtin_fmaf(rl(z3, k4), cv, acc3);
        }
      }
      float dv[4] = {acc0, acc1, acc2, acc3};
#pragma unroll
      for (int gi = 0; gi < 4; ++gi) {
        float d = __fsub_rn(__fadd_rn(ap[gi], bnj), 2.0f * dv[gi]);
        unsigned long long q = packdj(d, j_global);
#pragma unroll
        for (int off = 1; off < 64; off <<= 1) {
          unsigned long long q2 = __shfl_xor(q, off);
          q = q2 < q ? q2 : q;
        }
        if (lane == 0) atomicMin(&pk[p[gi]], q);
      }
    }
  }
}

__global__ __launch_bounds__(256) void k_gather(const float* __restrict__ ze,
                                                const float* __restrict__ cb,
                                                const unsigned long long* __restrict__ pk,
                                                float* __restrict__ out_zq,
                                                float* __restrict__ out_idx,
                                                float* __restrict__ part) {
  __shared__ float qrow[64][257];
  __shared__ int sidx[64];
  int tid = threadIdx.x;
  int p0 = blockIdx.x * 64;
  int b = p0 >> 10, hw0 = p0 & 1023;
  if (tid < 64) {
    int bi = (int)(unsigned int)(pk[p0 + tid] & 0xffffffffull);
    sidx[tid] = bi;
    out_idx[p0 + tid] = (float)bi;
  }
  __syncthreads();
  for (int r = 0; r < 64; ++r)
    qrow[r][tid] = cb[(size_t)sidx[r] * 256 + tid];
  __syncthreads();
  float lsum = 0.f;
  size_t zbase = (size_t)b * 262144 + hw0;
#pragma unroll 4
  for (int i = 0; i < 64; ++i) {
    int px = tid & 63;
    int c = i * 4 + (tid >> 6);
    float qv = qrow[px][c];
    size_t gi = zbase + (size_t)c * 1024 + px;
    float zev = ze[gi];
    out_zq[gi] = __fadd_rn(zev, __fsub_rn(qv, zev));
    float d = zev - qv;
    lsum = __builtin_fmaf(d, d, lsum);
  }
#pragma unroll
  for (int off = 32; off; off >>= 1) lsum += __shfl_xor(lsum, off, 64);
  __shared__ float wsum[4];
  if ((tid & 63) == 0) wsum[tid >> 6] = lsum;
  __syncthreads();
  if (tid == 0) part[blockIdx.x] = (wsum[0] + wsum[1]) + (wsum[2] + wsum[3]);
}

__global__ __launch_bounds__(256) void k_final(const float* __restrict__ part,
                                               float* __restrict__ out0) {
  int tid = threadIdx.x;
  float s = part[tid];
#pragma unroll
  for (int off = 32; off; off >>= 1) s += __shfl_xor(s, off, 64);
  __shared__ float wsum[4];
  if ((tid & 63) == 0) wsum[tid >> 6] = s;
  __syncthreads();
  if (tid == 0)
    out0[0] = 1.25f * ((wsum[0] + wsum[1]) + (wsum[2] + wsum[3])) / 4194304.0f;
}

extern "C" void kernel_launch(void* const* d_in, const int* in_sizes, int n_in,
                              void* d_out, int out_size, void* d_ws, size_t ws_size,
                              hipStream_t stream) {
  const float* ze = (const float*)d_in[0];
  const float* cb = (const float*)d_in[1];
  float* out = (float*)d_out;
  char* ws = (char*)d_ws;
  short* zebff = (short*)(ws + WS_ZEBF);
  short* cbbft = (short*)(ws + WS_CBBF);
  float* zef = (float*)(ws + WS_ZEF);
  float* bn = (float*)(ws + WS_BN);
  float* an = (float*)(ws + WS_AN);
  float* wsmin = (float*)(ws + WS_MIN);
  float* tau = (float*)(ws + WS_TAU);
  int* blist = (int*)(ws + WS_BLIST);
  int* bcnt = (int*)(ws + WS_BCNT);
  unsigned* bmaxu = (unsigned*)(ws + WS_BMAXU);
  unsigned long long* pk = (unsigned long long*)(ws + WS_PK);
  float* part = (float*)(ws + WS_PART);
  float* out_loss = out;
  float* out_zq = out + 1;
  float* out_idx = out + 1 + 4194304;

  k_cvt_ze<<<256, 256, 0, stream>>>(ze, zebff, zef, an);
  k_cvt_cb<<<128, 256, 0, stream>>>(cb, cbbft, bmaxu);
  k_bnorm<<<128, 256, 0, stream>>>(cb, bn, bmaxu);
  k_gemm<<<512, 256, 0, stream>>>(zebff, cbbft, bn, wsmin);
  k_tau<<<256, 256, 0, stream>>>(wsmin, an, bmaxu, tau, pk);
  k_compact<<<128, 256, 0, stream>>>(wsmin, tau, bcnt, blist);
  k_rescore_b<<<512, 256, 0, stream>>>(zef, cb, an, bn, bcnt, blist, pk);
  k_gather<<<256, 256, 0, stream>>>(ze, cb, pk, out_zq, out_idx, part);
  k_final<<<1, 256, 0, stream>>>(part, out_loss);
}

// Round 12
// 188.892 us; speedup vs baseline: 1.9111x; 1.0348x over previous
//
#include <hip/hip_runtime.h>
#include <hip/hip_bf16.h>

#define NPIX 16384
#define NVOC 8192
#define CHUNK 32

typedef short short8v __attribute__((ext_vector_type(8)));
typedef float floatx4 __attribute__((ext_vector_type(4)));

// ---- ws layout (bytes) ----
// region A (0..8 MB): zebf(frag) during cvt/gemm -> blist after gemm -> part
#define WS_ZEBF   0u          // 16384*256 bf16 = 8388608 (dead after k_gemm)
#define WS_BLIST  0u          // 128*16384 i32 = 8388608 (alias, post-gemm)
#define WS_PART   0u          // 256 f32 (alias, post-rescore; blist dead)
// region B: cbbft during gemm -> pk/tau after gemm
#define WS_CBBF   8388608u    // 8192*256 bf16 = 4194304 (dead after k_gemm)
#define WS_PK     8388608u    // 16384 u64 = 131072 (alias, post-gemm)
#define WS_TAU    8519680u    // 16384 f32 = 65536 (alias, post-gemm)
// persistent
#define WS_ZEF    12582912u   // 16384*256 f32 = 16777216
#define WS_MIN    29360128u   // 128*16384 f32 = 8388608
#define WS_BN     37748736u   // 8192 f32
#define WS_AN     37781504u   // 16384 f32
#define WS_BCNT   37847040u   // 128 i32 (pad to 512)
#define WS_BMAXU  37847552u   // 1 u32
#define WS_QCNT   37847556u   // 1 i32
#define WS_QUEUE  37847808u   // 131072 i32 = 524288 (worst-case need 65664)

__device__ __forceinline__ short f2bf(float v) {
  __bf16 h = (__bf16)v;
  return __builtin_bit_cast(short, h);
}

__device__ __forceinline__ float rl(float v, int l) {
  return __uint_as_float(__builtin_amdgcn_readlane(__float_as_uint(v), l));
}

__device__ __forceinline__ unsigned long long packdj(float d, int j) {
  return ((unsigned long long)__float_as_uint(d) << 32) | (unsigned int)j;
}

__device__ __forceinline__ void gll16(const void* g, void* l) {
  __builtin_amdgcn_global_load_lds(
      (const __attribute__((address_space(1))) void*)g,
      (__attribute__((address_space(3))) void*)l, 16, 0, 0);
}

// numpy pairwise-sum of 128 squares
__device__ __forceinline__ float np_pairwise128_sq(const float* x, int stride) {
  float r[8];
#pragma unroll
  for (int j = 0; j < 8; ++j) {
    float v = x[j * stride];
    r[j] = __fmul_rn(v, v);
  }
#pragma unroll
  for (int i = 1; i < 16; ++i) {
#pragma unroll
    for (int j = 0; j < 8; ++j) {
      float v = x[(i * 8 + j) * stride];
      r[j] = __fadd_rn(r[j], __fmul_rn(v, v));
    }
  }
  return __fadd_rn(__fadd_rn(__fadd_rn(r[0], r[1]), __fadd_rn(r[2], r[3])),
                   __fadd_rn(__fadd_rn(r[4], r[5]), __fadd_rn(r[6], r[7])));
}

// ||codebook_j||^2 (numpy order) + global max(bn) via atomicMax on bits
__global__ __launch_bounds__(256) void k_bnorm(const float* __restrict__ cb,
                                               float* __restrict__ bn,
                                               unsigned* __restrict__ bmaxu) {
  __shared__ float rows[64][257];
  int tid = threadIdx.x;
  int c0 = blockIdx.x * 64;
  for (int r = 0; r < 64; ++r)
    rows[r][tid] = cb[(size_t)(c0 + r) * 256 + tid];
  __syncthreads();
  if (tid < 64) {
    float a = np_pairwise128_sq(&rows[tid][0], 1);
    float b = np_pairwise128_sq(&rows[tid][128], 1);
    float v = __fadd_rn(a, b);
    bn[c0 + tid] = v;
    atomicMax(bmaxu, __float_as_uint(v));
  }
}

// ze [16][256][1024] fp32 -> zebf in MFMA-FRAGMENT order + zef (fp32) + an.
__global__ __launch_bounds__(256) void k_cvt_ze(const float* __restrict__ ze,
                                                short* __restrict__ zebff,
                                                float* __restrict__ zef,
                                                float* __restrict__ an) {
  __shared__ float t[64][132];
  int tid = threadIdx.x;
  int p0 = blockIdx.x * 64;
  int b = p0 >> 10, hw0 = p0 & 1023;
  const float* src = ze + (size_t)b * 262144 + hw0;
  float apart = 0.f;
  for (int half = 0; half < 2; ++half) {
    if (half) __syncthreads();
    {
      int hw = tid & 63, cq = tid >> 6;
#pragma unroll
      for (int i = 0; i < 32; ++i) {
        int cl = i * 4 + cq;
        t[hw][cl] = src[(size_t)(half * 128 + cl) * 1024 + hw];
      }
    }
    __syncthreads();
    {
      int r = tid >> 2, cg = tid & 3;
      float* fd = zef + (size_t)(p0 + r) * 256 + half * 128 + cg * 32;
#pragma unroll
      for (int s = 0; s < 8; ++s) {
        float4 v = *reinterpret_cast<const float4*>(&t[r][cg * 32 + s * 4]);
        *reinterpret_cast<float4*>(fd + s * 4) = v;
      }
    }
    {
      int pg_l = tid >> 6, l = tid & 63;
      size_t pg = (size_t)(p0 >> 4) + pg_l;
      int lr = l & 15, lg = l >> 4;
#pragma unroll
      for (int kl = 0; kl < 4; ++kl) {
        int ks = half * 4 + kl;
        short8v v8;
#pragma unroll
        for (int e = 0; e < 8; ++e)
          v8[e] = f2bf(t[pg_l * 16 + lr][kl * 32 + lg * 8 + e]);
        *reinterpret_cast<short8v*>(zebff + (pg * 8 + ks) * 512 + l * 8) = v8;
      }
    }
    if (tid < 64) {
      float a = np_pairwise128_sq(&t[tid][0], 1);
      apart = half ? __fadd_rn(apart, a) : a;
    }
  }
  if (tid < 64) an[p0 + tid] = apart;
}

// cb -> bf16 in per-tile K-MAJOR layout; also init bmax/qcnt.
__global__ __launch_bounds__(256) void k_cvt_cb(const float* __restrict__ cb,
                                                short* __restrict__ cbbft,
                                                unsigned* __restrict__ bmaxu,
                                                int* __restrict__ qcnt) {
  __shared__ short t[64][264];
  int tid = threadIdx.x;
  if (blockIdx.x == 0 && tid == 0) {
    bmaxu[0] = 0u;
    qcnt[0] = 0;
  }
  int j0 = blockIdx.x * 64;
  {
    int col = tid >> 2, q = tid & 3;
    const float* src = cb + (size_t)(j0 + col) * 256 + q * 64;
#pragma unroll
    for (int i = 0; i < 8; ++i) {
      float4 a = *reinterpret_cast<const float4*>(src + i * 8);
      float4 b = *reinterpret_cast<const float4*>(src + i * 8 + 4);
      short8v v;
      v[0] = f2bf(a.x); v[1] = f2bf(a.y); v[2] = f2bf(a.z); v[3] = f2bf(a.w);
      v[4] = f2bf(b.x); v[5] = f2bf(b.y); v[6] = f2bf(b.z); v[7] = f2bf(b.w);
      *reinterpret_cast<short8v*>(&t[col][q * 64 + i * 8]) = v;
    }
  }
  __syncthreads();
  short* dst = cbbft + (size_t)blockIdx.x * 16384;
#pragma unroll
  for (int s = 0; s < 8; ++s) {
    int cid = tid + s * 256;
    int kc = cid >> 6, c2 = cid & 63;
    short8v v = *reinterpret_cast<const short8v*>(&t[c2][kc * 8]);
    *reinterpret_cast<short8v*>(dst + cid * 8) = v;
  }
}

// Swapped-operand bf16 MFMA distance GEMM, 2 blocks/CU. (unchanged from R11)
__global__ __launch_bounds__(256, 2) void k_gemm(const short* __restrict__ zebff,
                                                 const short* __restrict__ cbbft,
                                                 const float* __restrict__ bn,
                                                 float* __restrict__ wsmin) {
  __shared__ short lds[32768];   // 2 x 32 KB B-tile buffers
  __shared__ float bnlds[1024];  // octant bn
  int tid = threadIdx.x;
  int lane = tid & 63, w = tid >> 6;
  int g = lane >> 4, r16 = lane & 15;
  int oct = blockIdx.x & 7, chunk = blockIdx.x >> 3;
  int p0 = chunk * 256;
  int ncol0 = oct * 1024;

  short8v pix[4][8];
  {
    const short* base = zebff + ((size_t)(p0 >> 4) + w * 4) * 4096 + lane * 8;
#pragma unroll
    for (int pf = 0; pf < 4; ++pf)
#pragma unroll
      for (int ks = 0; ks < 8; ++ks)
        pix[pf][ks] =
            *reinterpret_cast<const short8v*>(base + pf * 4096 + ks * 512);
  }
  gll16(bn + ncol0 + tid * 4, &bnlds[tid * 4]);

#define STAGE(t, boff)                                                         \
  {                                                                            \
    const short* src_ = cbbft + (size_t)(oct * 16 + (t)) * 16384;              \
    _Pragma("unroll") for (int s = 0; s < 8; ++s) {                            \
      int cid_ = tid + s * 256;                                                \
      gll16(src_ + cid_ * 8, &lds[(boff) + cid_ * 8]);                         \
    }                                                                          \
  }
  STAGE(0, 0)
  asm volatile("s_waitcnt vmcnt(0)" ::: "memory");
  __builtin_amdgcn_s_barrier();

  float* wbase = wsmin + (size_t)(oct * 16) * NPIX + p0 + w * 64 + r16;

  for (int t = 0; t < 16; ++t) {
    int bA = (t & 1) * 16384;
    int bC = bA ^ 16384;
    if (t < 15) STAGE(t + 1, bC)
    float4 bnv[4];
#pragma unroll
    for (int cf = 0; cf < 4; ++cf)
      bnv[cf] =
          *reinterpret_cast<const float4*>(&bnlds[t * 64 + cf * 16 + g * 4]);
    floatx4 acc[4][4];
#pragma unroll
    for (int cf = 0; cf < 4; ++cf)
#pragma unroll
      for (int pf = 0; pf < 4; ++pf) acc[cf][pf] = floatx4{0.f, 0.f, 0.f, 0.f};
    __builtin_amdgcn_s_setprio(1);
#pragma unroll
    for (int ks = 0; ks < 8; ++ks) {  // k-ascending: bit-identical chains
      short8v cfr[4];
#pragma unroll
      for (int cf = 0; cf < 4; ++cf)
        cfr[cf] = *reinterpret_cast<const short8v*>(
            &lds[bA + (((ks * 4 + g) * 64) + cf * 16 + r16) * 8]);
#pragma unroll
      for (int cf = 0; cf < 4; ++cf)
#pragma unroll
        for (int pf = 0; pf < 4; ++pf)
          acc[cf][pf] = __builtin_amdgcn_mfma_f32_16x16x32_bf16(
              cfr[cf], pix[pf][ks], acc[cf][pf], 0, 0, 0);
    }
    __builtin_amdgcn_s_setprio(0);
    float pmin[4];
#pragma unroll
    for (int pf = 0; pf < 4; ++pf) {
      float m_ = 3.4e38f;
#pragma unroll
      for (int cf = 0; cf < 4; ++cf)
#pragma unroll
        for (int rr = 0; rr < 4; ++rr)
          m_ = fminf(m_, __builtin_fmaf(-2.0f, acc[cf][pf][rr], bnv[cf][rr]));
      m_ = fminf(m_, __shfl_xor(m_, 16));
      m_ = fminf(m_, __shfl_xor(m_, 32));
      pmin[pf] = m_;
    }
    if (lane < 16) {
#pragma unroll
      for (int pf = 0; pf < 4; ++pf)
        wbase[(size_t)t * NPIX + pf * 16] = pmin[pf];
    }
    asm volatile("s_waitcnt vmcnt(0)" ::: "memory");
    __builtin_amdgcn_s_barrier();
  }
#undef STAGE
}

// per-pixel global min over 128 colblocks -> tau; init pk. No atomics.
__global__ __launch_bounds__(256) void k_tau(const float* __restrict__ wsmin,
                                             const float* __restrict__ an,
                                             const unsigned* __restrict__ bmaxu,
                                             float* __restrict__ tau,
                                             unsigned long long* __restrict__ pk) {
  __shared__ float sm[4][64];
  int tid = threadIdx.x;
  int px = tid & 63, q = tid >> 6;
  int p = blockIdx.x * 64 + px;
  float m0 = 3.4e38f, m1 = 3.4e38f, m2 = 3.4e38f, m3 = 3.4e38f;
#pragma unroll
  for (int i = 0; i < 8; ++i) {
    int c = q * 32 + i * 4;
    m0 = fminf(m0, wsmin[(size_t)c * NPIX + p]);
    m1 = fminf(m1, wsmin[(size_t)(c + 1) * NPIX + p]);
    m2 = fminf(m2, wsmin[(size_t)(c + 2) * NPIX + p]);
    m3 = fminf(m3, wsmin[(size_t)(c + 3) * NPIX + p]);
  }
  sm[q][px] = fminf(fminf(m0, m1), fminf(m2, m3));
  __syncthreads();
  if (tid < 64) {
    float m = fminf(fminf(sm[0][tid], sm[1][tid]), fminf(sm[2][tid], sm[3][tid]));
    float bmaxf = sqrtf(__uint_as_float(bmaxu[0]));
    tau[p] = m + 0.017f * sqrtf(an[p]) * bmaxf + 2e-4f;
    pk[p] = ~0ull;
  }
}

// per-colblock compaction of flagged pixels, ascending p, zero contention;
// emits chunk descriptors (c | chunk<<16) into the work queue.
__global__ __launch_bounds__(256) void k_compact(const float* __restrict__ wsmin,
                                                 const float* __restrict__ tau,
                                                 int* __restrict__ bcnt,
                                                 int* __restrict__ blist,
                                                 int* __restrict__ qcnt,
                                                 int* __restrict__ queue) {
  __shared__ int wbase[4];
  __shared__ int running;
  int c = blockIdx.x;
  const float* row = wsmin + (size_t)c * NPIX;
  int* dst = blist + (size_t)c * NPIX;
  int tid = threadIdx.x;
  int lane = tid & 63, wv = tid >> 6;
  if (tid == 0) running = 0;
  __syncthreads();
  for (int base = 0; base < NPIX; base += 256) {
    int p = base + tid;
    bool flag = row[p] <= tau[p];
    unsigned long long mask = __ballot(flag);
    int cnt = __popcll(mask);
    int pre = __popcll(mask & ((1ull << lane) - 1ull));
    if (lane == 0) wbase[wv] = cnt;
    __syncthreads();
    if (tid == 0) {
      int r = running;
#pragma unroll
      for (int w2 = 0; w2 < 4; ++w2) {
        int t = wbase[w2];
        wbase[w2] = r;
        r += t;
      }
      running = r;
    }
    __syncthreads();
    if (flag) dst[wbase[wv] + pre] = p;
    __syncthreads();
  }
  if (tid == 0) {
    int n = running;
    bcnt[c] = n;
    int nch = (n + CHUNK - 1) / CHUNK;
    if (nch > 0) {
      int q0 = atomicAdd(qcnt, nch);
      for (int i = 0; i < nch; ++i) queue[q0 + i] = c | (i << 16);
    }
  }
}

// queue-driven exact fp32 rescore: persistent 512 blocks stride the dense
// chunk queue (balanced). Stage 64-code block in LDS; lane owns one code;
// readlane broadcast + serial k-ascending fmaf (bit-identical to R11);
// lex-min (d,j) via 64-bit atomicMin (commutative -> deterministic).
__global__ __launch_bounds__(256) void k_rescore_b(
    const float* __restrict__ zef, const float* __restrict__ cb,
    const float* __restrict__ an, const float* __restrict__ bn,
    const int* __restrict__ bcnt, const int* __restrict__ blist,
    const int* __restrict__ qcnt, const int* __restrict__ queue,
    unsigned long long* __restrict__ pk) {
  __shared__ float cst[256][64];
  int tid = threadIdx.x;
  int lane = tid & 63, wv = tid >> 6;
  int nq = qcnt[0];
  for (int qi = blockIdx.x; qi < nq; qi += 512) {
    int e = queue[qi];
    int c = e & 0xffff;
    int chunk = e >> 16;
    int n = bcnt[c];
    int base = chunk * CHUNK;
    int cnt_here = min(CHUNK, n - base);
    __syncthreads();  // WAR vs previous entry's readers
    {
      int j = tid >> 2, kq = tid & 3;
      const float* src = cb + (size_t)(c * 64 + j) * 256 + kq * 64;
#pragma unroll
      for (int i = 0; i < 16; ++i) {
        float4 v = *reinterpret_cast<const float4*>(src + i * 4);
        int k = kq * 64 + i * 4;
        cst[k][j] = v.x; cst[k + 1][j] = v.y;
        cst[k + 2][j] = v.z; cst[k + 3][j] = v.w;
      }
    }
    __syncthreads();
    int j_global = c * 64 + lane;
    float bnj = bn[j_global];
    for (int g0 = wv * 4; g0 < cnt_here; g0 += 16) {
      int p[4];
      float4 z[4];
      float ap[4];
#pragma unroll
      for (int gi = 0; gi < 4; ++gi) {
        int idx = base + min(g0 + gi, cnt_here - 1);
        p[gi] = blist[(size_t)c * NPIX + idx];
        z[gi] = *reinterpret_cast<const float4*>(zef + (size_t)p[gi] * 256 +
                                                 lane * 4);
        ap[gi] = an[p[gi]];
      }
      float acc0 = 0.f, acc1 = 0.f, acc2 = 0.f, acc3 = 0.f;
#pragma unroll 8
      for (int k4 = 0; k4 < 64; ++k4) {
#pragma unroll
        for (int kk = 0; kk < 4; ++kk) {
          float cv = cst[k4 * 4 + kk][lane];
          float z0 = (kk == 0) ? z[0].x : (kk == 1) ? z[0].y : (kk == 2) ? z[0].z : z[0].w;
          float z1 = (kk == 0) ? z[1].x : (kk == 1) ? z[1].y : (kk == 2) ? z[1].z : z[1].w;
          float z2 = (kk == 0) ? z[2].x : (kk == 1) ? z[2].y : (kk == 2) ? z[2].z : z[2].w;
          float z3 = (kk == 0) ? z[3].x : (kk == 1) ? z[3].y : (kk == 2) ? z[3].z : z[3].w;
          acc0 = __builtin_fmaf(rl(z0, k4), cv, acc0);
          acc1 = __builtin_fmaf(rl(z1, k4), cv, acc1);
          acc2 = __builtin_fmaf(rl(z2, k4), cv, acc2);
          acc3 = __builtin_fmaf(rl(z3, k4), cv, acc3);
        }
      }
      float dv[4] = {acc0, acc1, acc2, acc3};
#pragma unroll
      for (int gi = 0; gi < 4; ++gi) {
        float d = __fsub_rn(__fadd_rn(ap[gi], bnj), 2.0f * dv[gi]);
        unsigned long long q = packdj(d, j_global);
#pragma unroll
        for (int off = 1; off < 64; off <<= 1) {
          unsigned long long q2 = __shfl_xor(q, off);
          q = q2 < q ? q2 : q;
        }
        if (lane == 0) atomicMin(&pk[p[gi]], q);
      }
    }
  }
}

__global__ __launch_bounds__(256) void k_gather(const float* __restrict__ ze,
                                                const float* __restrict__ cb,
                                                const unsigned long long* __restrict__ pk,
                                                float* __restrict__ out_zq,
                                                float* __restrict__ out_idx,
                                                float* __restrict__ part) {
  __shared__ float qrow[64][257];
  __shared__ int sidx[64];
  int tid = threadIdx.x;
  int p0 = blockIdx.x * 64;
  int b = p0 >> 10, hw0 = p0 & 1023;
  if (tid < 64) {
    int bi = (int)(unsigned int)(pk[p0 + tid] & 0xffffffffull);
    sidx[tid] = bi;
    out_idx[p0 + tid] = (float)bi;
  }
  __syncthreads();
  for (int r = 0; r < 64; ++r)
    qrow[r][tid] = cb[(size_t)sidx[r] * 256 + tid];
  __syncthreads();
  float lsum = 0.f;
  size_t zbase = (size_t)b * 262144 + hw0;
#pragma unroll 4
  for (int i = 0; i < 64; ++i) {
    int px = tid & 63;
    int c = i * 4 + (tid >> 6);
    float qv = qrow[px][c];
    size_t gi = zbase + (size_t)c * 1024 + px;
    float zev = ze[gi];
    out_zq[gi] = __fadd_rn(zev, __fsub_rn(qv, zev));
    float d = zev - qv;
    lsum = __builtin_fmaf(d, d, lsum);
  }
#pragma unroll
  for (int off = 32; off; off >>= 1) lsum += __shfl_xor(lsum, off, 64);
  __shared__ float wsum[4];
  if ((tid & 63) == 0) wsum[tid >> 6] = lsum;
  __syncthreads();
  if (tid == 0) part[blockIdx.x] = (wsum[0] + wsum[1]) + (wsum[2] + wsum[3]);
}

__global__ __launch_bounds__(256) void k_final(const float* __restrict__ part,
                                               float* __restrict__ out0) {
  int tid = threadIdx.x;
  float s = part[tid];
#pragma unroll
  for (int off = 32; off; off >>= 1) s += __shfl_xor(s, off, 64);
  __shared__ float wsum[4];
  if ((tid & 63) == 0) wsum[tid >> 6] = s;
  __syncthreads();
  if (tid == 0)
    out0[0] = 1.25f * ((wsum[0] + wsum[1]) + (wsum[2] + wsum[3])) / 4194304.0f;
}

extern "C" void kernel_launch(void* const* d_in, const int* in_sizes, int n_in,
                              void* d_out, int out_size, void* d_ws, size_t ws_size,
                              hipStream_t stream) {
  const float* ze = (const float*)d_in[0];
  const float* cb = (const float*)d_in[1];
  float* out = (float*)d_out;
  char* ws = (char*)d_ws;
  short* zebff = (short*)(ws + WS_ZEBF);
  short* cbbft = (short*)(ws + WS_CBBF);
  float* zef = (float*)(ws + WS_ZEF);
  float* bn = (float*)(ws + WS_BN);
  float* an = (float*)(ws + WS_AN);
  float* wsmin = (float*)(ws + WS_MIN);
  float* tau = (float*)(ws + WS_TAU);
  int* blist = (int*)(ws + WS_BLIST);
  int* bcnt = (int*)(ws + WS_BCNT);
  unsigned* bmaxu = (unsigned*)(ws + WS_BMAXU);
  int* qcnt = (int*)(ws + WS_QCNT);
  int* queue = (int*)(ws + WS_QUEUE);
  unsigned long long* pk = (unsigned long long*)(ws + WS_PK);
  float* part = (float*)(ws + WS_PART);
  float* out_loss = out;
  float* out_zq = out + 1;
  float* out_idx = out + 1 + 4194304;

  k_cvt_ze<<<256, 256, 0, stream>>>(ze, zebff, zef, an);
  k_cvt_cb<<<128, 256, 0, stream>>>(cb, cbbft, bmaxu, qcnt);
  k_bnorm<<<128, 256, 0, stream>>>(cb, bn, bmaxu);
  k_gemm<<<512, 256, 0, stream>>>(zebff, cbbft, bn, wsmin);
  k_tau<<<256, 256, 0, stream>>>(wsmin, an, bmaxu, tau, pk);
  k_compact<<<128, 256, 0, stream>>>(wsmin, tau, bcnt, blist, qcnt, queue);
  k_rescore_b<<<512, 256, 0, stream>>>(zef, cb, an, bn, bcnt, blist, qcnt,
                                       queue, pk);
  k_gather<<<256, 256, 0, stream>>>(ze, cb, pk, out_zq, out_idx, part);
  k_final<<<1, 256, 0, stream>>>(part, out_loss);
}